// Round 7
// baseline (2491.007 us; speedup 1.0000x reference)
//
#include <hip/hip_runtime.h>
#include <math.h>

#define T_ 12
#define N_ 20000
#define E_ 320000
#define FIN_ 128
#define H_ 256
#define G_ 256
#define C_ 10
#define ECH 8
#define EPC (E_ / ECH)  // 40000 edges per chunk

typedef __attribute__((ext_vector_type(8))) short bf16x8;
typedef __attribute__((ext_vector_type(4))) float f32x4;

// ---------------- workspace layout (bytes) ----------------
static const size_t OFF_EMB   = 0;          // T*256 f32 (zeroed each launch)
static const size_t ZERO_BYTES= 12288;
static const size_t OFF_DINV  = 12288;      // T*N f32
static const size_t OFF_DEGP  = 972288;     // T*ECH*N f32 partial degrees
static const size_t OFF_CNT16 = 8652288;    // T*ECH*N u16 partial counts
static const size_t OFF_CUMC  = 12492288;   // T*ECH*(N+1) u32 chunk-major slot bases
static const size_t OFF_EROW  = 20172672;   // T*E i32 (chunk-major CSR)
static const size_t OFF_ENORM = 35532672;   // T*E f32
static const size_t OFF_W1BT  = 50892672;   // 256x128 bf16
static const size_t OFF_W2BT  = 50958208;   // 256x256 bf16
static const size_t OFF_WIHT  = 51089280;   // 256x768 f32
static const size_t OFF_WHHT  = 51875712;   // 256x768 f32
static const size_t OFF_GX    = 52662144;   // 12x768 f32
static const size_t OFF_XBT   = 52699008;   // N*128 bf16
static const size_t OFF_P     = 57819008;   // N*256 bf16
static const size_t OFF_Q     = 68059008;   // N*256 bf16
// end ~78.3 MB

__device__ __forceinline__ float bf2f(unsigned short u) {
  return __uint_as_float(((unsigned int)u) << 16);
}
__device__ __forceinline__ unsigned short f2bf(float f) {
  unsigned int u = __float_as_uint(f);
  unsigned int r = (u + 0x7FFFu + ((u >> 16) & 1u)) >> 16;  // RNE
  return (unsigned short)r;
}
__device__ __forceinline__ float bflo(unsigned int u) { return __uint_as_float(u << 16); }
__device__ __forceinline__ float bfhi(unsigned int u) { return __uint_as_float(u & 0xFFFF0000u); }
__device__ __forceinline__ unsigned int packbf(float lo, float hi) {
  return (unsigned int)f2bf(lo) | ((unsigned int)f2bf(hi) << 16);
}

// ---------------- partial histogram: block (t, ech) owns edges [ech*EPC, +EPC) ----------------
__global__ __launch_bounds__(1024) void histp(const int* __restrict__ ei,
                                              const float* __restrict__ ea,
                                              float* __restrict__ degp,
                                              unsigned short* __restrict__ cnt16) {
  __shared__ float degs[N_];            // 80 KB
  __shared__ unsigned int cntp[N_ / 2]; // 40 KB (two u16 counters per word)
  const int t = blockIdx.x, ech = blockIdx.y;
  const int tid = threadIdx.x;
  for (int i = tid; i < N_; i += 1024) degs[i] = 0.f;
  for (int i = tid; i < N_ / 2; i += 1024) cntp[i] = 0u;
  __syncthreads();
  const int* col = ei + (size_t)t * 2 * E_ + E_ + ech * EPC;
  const float* wt = ea + (size_t)t * E_ + ech * EPC;
  for (int e = tid; e < EPC; e += 1024) {
    int c = col[e];
    atomicAdd(&degs[c], wt[e]);
    atomicAdd(&cntp[c >> 1], 1u << ((c & 1) * 16));
  }
  __syncthreads();
  float* dp = degp + ((size_t)t * ECH + ech) * N_;
  unsigned short* cp16 = cnt16 + ((size_t)t * ECH + ech) * N_;
  for (int i = tid; i < N_; i += 1024) {
    dp[i] = degs[i];
    cp16[i] = (unsigned short)((cntp[i >> 1] >> ((i & 1) * 16)) & 0xFFFFu);
  }
}

// ---------------- per-chunk prefix scan: cumc[t][ech][n], base = ech*EPC ----------------
__global__ __launch_bounds__(1024) void scanC(const unsigned short* __restrict__ cnt16,
                                              unsigned int* __restrict__ cumc) {
  const int t = blockIdx.x, ech = blockIdx.y;
  __shared__ int s[1024];
  const int tid = threadIdx.x;
  const unsigned short* cc = cnt16 + ((size_t)t * ECH + ech) * N_;
  unsigned int* cm = cumc + ((size_t)t * ECH + ech) * (N_ + 1);
  int base = ech * EPC;
  for (int c0 = 0; c0 < N_; c0 += 1024) {
    int i = c0 + tid;
    int v = (i < N_) ? (int)cc[i] : 0;
    s[tid] = v;
    __syncthreads();
    for (int off = 1; off < 1024; off <<= 1) {
      int add = (tid >= off) ? s[tid - off] : 0;
      __syncthreads();
      s[tid] += add;
      __syncthreads();
    }
    if (i < N_) cm[i] = (unsigned int)(base + s[tid] - v);  // exclusive
    base += s[1023];
    __syncthreads();
  }
  if (tid == 0) cm[N_] = (unsigned int)base;  // == (ech+1)*EPC
}

// ---------------- total degree -> dinv ----------------
__global__ __launch_bounds__(256) void dinvk(const float* __restrict__ degp,
                                             float* __restrict__ dinv) {
  int idx = blockIdx.x * 256 + threadIdx.x;
  if (idx >= T_ * N_) return;
  int t = idx / N_, n = idx - t * N_;
  float dg = 0.f;
#pragma unroll
  for (int ch = 0; ch < ECH; ++ch) dg += degp[((size_t)t * ECH + ch) * N_ + n];
  dinv[idx] = rsqrtf(dg + 1.0f);
}

// ---------------- CSR fill: block (t,ech) scatters only in its private 320KB window ----------------
__global__ __launch_bounds__(1024) void fillC(const int* __restrict__ ei,
                                              const float* __restrict__ ea,
                                              const unsigned int* __restrict__ cumc,
                                              const float* __restrict__ dinv,
                                              int* __restrict__ erow,
                                              float* __restrict__ enorm) {
  __shared__ unsigned int off[N_];  // 80 KB
  const int t = blockIdx.x, ech = blockIdx.y;
  const int tid = threadIdx.x;
  const unsigned int* cm = cumc + ((size_t)t * ECH + ech) * (N_ + 1);
  for (int i = tid; i < N_; i += 1024) off[i] = cm[i];
  __syncthreads();
  const int* rowp = ei + (size_t)t * 2 * E_ + ech * EPC;
  const int* colp = rowp + E_;
  const float* wt = ea + (size_t)t * E_ + ech * EPC;
  const float* dv = dinv + (size_t)t * N_;
  int* er = erow + (size_t)t * E_;
  float* en = enorm + (size_t)t * E_;
  for (int e = tid; e < EPC; e += 1024) {
    int r = rowp[e], c = colp[e];
    unsigned int pos = atomicAdd(&off[c], 1u);
    er[pos] = r;
    en[pos] = dv[r] * wt[e] * dv[c];
  }
}

// ---------------- weight prep ----------------
__global__ __launch_bounds__(256) void prep_kernel(const float* __restrict__ W1,
                                                   const float* __restrict__ W2,
                                                   const float* __restrict__ Wih,
                                                   const float* __restrict__ Whh,
                                                   unsigned short* __restrict__ W1bT,
                                                   unsigned short* __restrict__ W2bT,
                                                   float* __restrict__ WihT,
                                                   float* __restrict__ WhhT) {
  int idx = blockIdx.x * 256 + threadIdx.x;
  if (idx < 32768) {
    int n = idx >> 7, k = idx & 127;
    W1bT[idx] = f2bf(W1[k * 256 + n]);
  } else if (idx < 98304) {
    int j = idx - 32768;
    int n = j >> 8, k = j & 255;
    W2bT[j] = f2bf(W2[k * 256 + n]);
  } else if (idx < 294912) {
    int j = idx - 98304;
    int k = j / 768, c = j - k * 768;
    WihT[j] = Wih[c * 256 + k];
  } else if (idx < 491520) {
    int j = idx - 294912;
    int k = j / 768, c = j - k * 768;
    WhhT[j] = Whh[c * 256 + k];
  }
}

// ---------------- cast x_t fp32 -> bf16 ----------------
__global__ __launch_bounds__(256) void castx_kernel(const float* __restrict__ x,
                                                    unsigned short* __restrict__ xb) {
  int idx = blockIdx.x * 256 + threadIdx.x;
  float4 v = ((const float4*)x)[idx];
  ushort4 o;
  o.x = f2bf(v.x); o.y = f2bf(v.y); o.z = f2bf(v.z); o.w = f2bf(v.w);
  ((ushort4*)xb)[idx] = o;
}

// ---------------- gather aggregate over 8 chunk-segments per node ----------------
__global__ __launch_bounds__(256) void agg128(const unsigned short* __restrict__ h,
                                              unsigned short* __restrict__ o,
                                              const int* __restrict__ erow,
                                              const float* __restrict__ enorm,
                                              const unsigned int* __restrict__ cm,  // [ECH][N+1]
                                              const float* __restrict__ dinv) {
  const int node = blockIdx.x * 4 + (threadIdx.x >> 6);
  const int lane = threadIdx.x & 63;
  float a0 = 0.f, a1 = 0.f;
#pragma unroll
  for (int ech = 0; ech < ECH; ++ech) {
    const unsigned int* row = cm + (size_t)ech * (N_ + 1) + node;
    const int s0 = row[0], s1 = row[1];
    for (int i = s0; i < s1; ++i) {
      const int r = erow[i];
      const float nm = enorm[i];
      unsigned int u = *(const unsigned int*)&h[(size_t)r * 128 + lane * 2];
      a0 = fmaf(nm, bflo(u), a0);
      a1 = fmaf(nm, bfhi(u), a1);
    }
  }
  const float di = dinv[node];
  const float sw = di * di;
  unsigned int us = *(const unsigned int*)&h[(size_t)node * 128 + lane * 2];
  a0 = fmaf(sw, bflo(us), a0);
  a1 = fmaf(sw, bfhi(us), a1);
  *(unsigned int*)&o[(size_t)node * 128 + lane * 2] = packbf(a0, a1);
}

__global__ __launch_bounds__(256) void agg256(const unsigned short* __restrict__ h,
                                              unsigned short* __restrict__ o,
                                              const int* __restrict__ erow,
                                              const float* __restrict__ enorm,
                                              const unsigned int* __restrict__ cm,  // [ECH][N+1]
                                              const float* __restrict__ dinv) {
  const int node = blockIdx.x * 4 + (threadIdx.x >> 6);
  const int lane = threadIdx.x & 63;
  float a0 = 0.f, a1 = 0.f, a2 = 0.f, a3 = 0.f;
#pragma unroll
  for (int ech = 0; ech < ECH; ++ech) {
    const unsigned int* row = cm + (size_t)ech * (N_ + 1) + node;
    const int s0 = row[0], s1 = row[1];
    for (int i = s0; i < s1; ++i) {
      const int r = erow[i];
      const float nm = enorm[i];
      uint2 u = *(const uint2*)&h[(size_t)r * 256 + lane * 4];
      a0 = fmaf(nm, bflo(u.x), a0);
      a1 = fmaf(nm, bfhi(u.x), a1);
      a2 = fmaf(nm, bflo(u.y), a2);
      a3 = fmaf(nm, bfhi(u.y), a3);
    }
  }
  const float di = dinv[node];
  const float sw = di * di;
  uint2 us = *(const uint2*)&h[(size_t)node * 256 + lane * 4];
  a0 = fmaf(sw, bflo(us.x), a0);
  a1 = fmaf(sw, bfhi(us.x), a1);
  a2 = fmaf(sw, bflo(us.y), a2);
  a3 = fmaf(sw, bfhi(us.y), a3);
  uint2 ov;
  ov.x = packbf(a0, a1);
  ov.y = packbf(a2, a3);
  *(uint2*)&o[(size_t)node * 256 + lane * 4] = ov;
}

// ---------------- bf16 MFMA GEMM: C[M,256] = relu(A[M,K] @ BT^T + bias) ----------------
// block: 64 rows x 128 cols, 4 waves (wave w: rows (w>>1)*32, cols (w&1)*64)
template <int K>
__global__ __launch_bounds__(256) void gemm_bf16(const unsigned short* __restrict__ A,
                                                 const unsigned short* __restrict__ BT,  // [256][K]
                                                 const float* __restrict__ bias,
                                                 unsigned short* __restrict__ C, int M) {
  constexpr int LD = K + 8;  // +8 bf16 pad: rows land 4 banks apart -> 2-way (free)
  __shared__ unsigned short As[64 * LD];
  const int tid = threadIdx.x;
  const int bm = blockIdx.x * 64;
  const int bn = blockIdx.y * 128;
  {
    constexpr int CPR = K / 8;             // 16B chunks per row
    constexpr int CH = 64 * CPR / 256;     // chunks per thread
#pragma unroll
    for (int i = 0; i < CH; ++i) {
      int chunk = tid + i * 256;
      int r = chunk / CPR;
      int ck = (chunk - r * CPR) * 8;
      int row = bm + r;
      if (row >= M) row = M - 1;
      *(bf16x8*)&As[r * LD + ck] = *(const bf16x8*)&A[(size_t)row * K + ck];
    }
  }
  __syncthreads();
  const int w = tid >> 6, l = tid & 63;
  const int l16 = l & 15, lk = l >> 4;
  const int rbase = (w >> 1) * 32;
  const int colbase = bn + (w & 1) * 64;
  f32x4 acc[2][4] = {};
  for (int ks = 0; ks < K; ks += 32) {
    bf16x8 a[2], b[4];
#pragma unroll
    for (int m = 0; m < 2; ++m)
      a[m] = *(const bf16x8*)&As[(rbase + m * 16 + l16) * LD + ks + lk * 8];
#pragma unroll
    for (int n = 0; n < 4; ++n)
      b[n] = *(const bf16x8*)&BT[(size_t)(colbase + n * 16 + l16) * K + ks + lk * 8];
#pragma unroll
    for (int m = 0; m < 2; ++m)
#pragma unroll
      for (int n = 0; n < 4; ++n)
        acc[m][n] = __builtin_amdgcn_mfma_f32_16x16x32_bf16(a[m], b[n], acc[m][n], 0, 0, 0);
  }
#pragma unroll
  for (int n = 0; n < 4; ++n) {
    int col = colbase + n * 16 + l16;
    float bv = bias[col];
#pragma unroll
    for (int m = 0; m < 2; ++m) {
      int row0 = bm + rbase + m * 16 + lk * 4;
#pragma unroll
      for (int r = 0; r < 4; ++r) {
        int row = row0 + r;
        if (row < M) {
          float v = fmaxf(acc[m][n][r] + bv, 0.f);
          C[(size_t)row * 256 + col] = f2bf(v);
        }
      }
    }
  }
}

// ---------------- mean pool (bf16 in) ----------------
__global__ __launch_bounds__(256) void mean_bf16(const unsigned short* __restrict__ h,
                                                 float* __restrict__ embp) {
  const int ch = threadIdx.x;
  float acc = 0.f;
  for (int n = blockIdx.x; n < N_; n += gridDim.x)
    acc += bf2f(h[(size_t)n * 256 + ch]);
  atomicAdd(&embp[ch], acc * (1.0f / N_));
}

// ---------------- GX[t] = Wih @ emb_t + bih ----------------
__global__ __launch_bounds__(768) void gx_kernel(const float* __restrict__ emb,
                                                 const float* __restrict__ WihT,  // [256][768]
                                                 const float* __restrict__ bih,
                                                 float* __restrict__ GX) {
  const int t = blockIdx.x;
  const int tid = threadIdx.x;
  __shared__ float se[256];
  if (tid < 256) se[tid] = emb[t * 256 + tid];
  __syncthreads();
  float p0 = 0.f, p1 = 0.f, p2 = 0.f, p3 = 0.f;
#pragma unroll 8
  for (int k = 0; k < 256; k += 4) {
    p0 = fmaf(WihT[(size_t)(k + 0) * 768 + tid], se[k + 0], p0);
    p1 = fmaf(WihT[(size_t)(k + 1) * 768 + tid], se[k + 1], p1);
    p2 = fmaf(WihT[(size_t)(k + 2) * 768 + tid], se[k + 2], p2);
    p3 = fmaf(WihT[(size_t)(k + 3) * 768 + tid], se[k + 3], p3);
  }
  GX[t * 768 + tid] = (p0 + p1) + (p2 + p3) + bih[tid];
}

// ---------------- sequential GRU + final linear ----------------
__global__ __launch_bounds__(768) void gru2_kernel(const float* __restrict__ GX,
                                                   const float* __restrict__ WhhT,  // [256][768]
                                                   const float* __restrict__ bhh,
                                                   const float* __restrict__ Wc,
                                                   const float* __restrict__ bc,
                                                   float* __restrict__ out) {
  __shared__ float sh[256];
  __shared__ float sgh[768];
  const int tid = threadIdx.x;
  if (tid < 256) sh[tid] = 0.f;
  __syncthreads();
  for (int t = 0; t < T_; ++t) {
    float p0 = 0.f, p1 = 0.f, p2 = 0.f, p3 = 0.f;
#pragma unroll 8
    for (int k = 0; k < 256; k += 4) {
      p0 = fmaf(WhhT[(size_t)(k + 0) * 768 + tid], sh[k + 0], p0);
      p1 = fmaf(WhhT[(size_t)(k + 1) * 768 + tid], sh[k + 1], p1);
      p2 = fmaf(WhhT[(size_t)(k + 2) * 768 + tid], sh[k + 2], p2);
      p3 = fmaf(WhhT[(size_t)(k + 3) * 768 + tid], sh[k + 3], p3);
    }
    sgh[tid] = (p0 + p1) + (p2 + p3) + bhh[tid];
    __syncthreads();
    if (tid < 256) {
      const float* gx = &GX[t * 768];
      float r = 1.f / (1.f + __expf(-(gx[tid] + sgh[tid])));
      float z = 1.f / (1.f + __expf(-(gx[256 + tid] + sgh[256 + tid])));
      float n = tanhf(gx[512 + tid] + r * sgh[512 + tid]);
      sh[tid] = (1.f - z) * n + z * sh[tid];
    }
    __syncthreads();
  }
  const int wv = tid >> 6, lane = tid & 63;
  if (wv < C_) {
    float p = 0.f;
#pragma unroll
    for (int i = 0; i < 4; ++i) {
      int j = lane + 64 * i;
      p += sh[j] * Wc[(size_t)j * C_ + wv];
    }
    for (int off = 32; off > 0; off >>= 1) p += __shfl_down(p, off);
    if (lane == 0) out[wv] = p + bc[wv];
  }
}

extern "C" void kernel_launch(void* const* d_in, const int* in_sizes, int n_in,
                              void* d_out, int out_size, void* d_ws, size_t ws_size,
                              hipStream_t stream) {
  const float* x   = (const float*)d_in[0];
  const int*   ei  = (const int*)d_in[1];
  const float* ea  = (const float*)d_in[2];
  const float* W1  = (const float*)d_in[3];
  const float* b1  = (const float*)d_in[4];
  const float* W2  = (const float*)d_in[5];
  const float* b2  = (const float*)d_in[6];
  const float* Wih = (const float*)d_in[7];
  const float* Whh = (const float*)d_in[8];
  const float* bih = (const float*)d_in[9];
  const float* bhh = (const float*)d_in[10];
  const float* Wc  = (const float*)d_in[11];
  const float* bc  = (const float*)d_in[12];
  float* out = (float*)d_out;

  char* w = (char*)d_ws;
  float* emb   = (float*)(w + OFF_EMB);
  float* dinv  = (float*)(w + OFF_DINV);
  float* degp  = (float*)(w + OFF_DEGP);
  unsigned short* cnt16 = (unsigned short*)(w + OFF_CNT16);
  unsigned int* cumc = (unsigned int*)(w + OFF_CUMC);
  int*   erow  = (int*)(w + OFF_EROW);
  float* enorm = (float*)(w + OFF_ENORM);
  unsigned short* W1bT = (unsigned short*)(w + OFF_W1BT);
  unsigned short* W2bT = (unsigned short*)(w + OFF_W2BT);
  float* WihT  = (float*)(w + OFF_WIHT);
  float* WhhT  = (float*)(w + OFF_WHHT);
  float* GX    = (float*)(w + OFF_GX);
  unsigned short* xbt = (unsigned short*)(w + OFF_XBT);
  unsigned short* P   = (unsigned short*)(w + OFF_P);
  unsigned short* Q   = (unsigned short*)(w + OFF_Q);

  hipMemsetAsync(d_ws, 0, ZERO_BYTES, stream);

  prep_kernel<<<1920, 256, 0, stream>>>(W1, W2, Wih, Whh, W1bT, W2bT, WihT, WhhT);

  dim3 csr_grid(T_, ECH);
  histp<<<csr_grid, 1024, 0, stream>>>(ei, ea, degp, cnt16);
  scanC<<<csr_grid, 1024, 0, stream>>>(cnt16, cumc);
  dinvk<<<(T_ * N_ + 255) / 256, 256, 0, stream>>>(degp, dinv);
  fillC<<<csr_grid, 1024, 0, stream>>>(ei, ea, cumc, dinv, erow, enorm);

  dim3 gemm_grid((N_ + 63) / 64, 2);
  for (int t = 0; t < T_; ++t) {
    const unsigned int* cmt = cumc + (size_t)t * ECH * (N_ + 1);
    const int* ert = erow + (size_t)t * E_;
    const float* ent = enorm + (size_t)t * E_;
    const float* dvt = dinv + (size_t)t * N_;
    castx_kernel<<<2500, 256, 0, stream>>>(x + (size_t)t * N_ * FIN_, xbt);
    agg128<<<N_ / 4, 256, 0, stream>>>(xbt, P, ert, ent, cmt, dvt);
    gemm_bf16<FIN_><<<gemm_grid, 256, 0, stream>>>(P, W1bT, b1, Q, N_);
    agg256<<<N_ / 4, 256, 0, stream>>>(Q, P, ert, ent, cmt, dvt);
    gemm_bf16<H_><<<gemm_grid, 256, 0, stream>>>(P, W2bT, b2, Q, N_);
    mean_bf16<<<128, 256, 0, stream>>>(Q, emb + t * H_);
  }
  gx_kernel<<<T_, 768, 0, stream>>>(emb, WihT, bih, GX);
  gru2_kernel<<<1, 768, 0, stream>>>(GX, WhhT, bhh, Wc, bc, out);
}

// Round 8
// 1847.462 us; speedup vs baseline: 1.3483x; 1.3483x over previous
//
#include <hip/hip_runtime.h>
#include <hip/hip_fp16.h>
#include <math.h>

#define T_ 12
#define N_ 20000
#define E_ 320000
#define FIN_ 128
#define H_ 256
#define G_ 256
#define C_ 10
#define ECH 8
#define EPC (E_ / ECH)
#define NB 16
#define BN (N_ / NB)   // 1250 nodes per bucket
#define CAP 24000      // LDS staging capacity (recs); overflow -> direct store

typedef __attribute__((ext_vector_type(8))) short bf16x8;
typedef __attribute__((ext_vector_type(4))) float f32x4;

// ---------------- workspace layout (bytes) ----------------
static const size_t OFF_EMB   = 0;          // T*256 f32 (zeroed each launch)
static const size_t ZERO_BYTES= 12288;
static const size_t OFF_DINV  = 12288;      // T*N f32
static const size_t OFF_CP    = 972288;     // T*(N+1) i32 (padded)
static const size_t OFF_DEGP  = 1932544;    // T*ECH*N f32 partial degrees
static const size_t OFF_CNT16 = 9612544;    // T*ECH*N u16 partial counts
static const size_t OFF_EREC  = 13452544;   // T*E u32 packed (row u16 | enorm f16)
static const size_t OFF_W1BT  = 28812544;   // 256x128 bf16
static const size_t OFF_W2BT  = 28878080;   // 256x256 bf16
static const size_t OFF_WIHT  = 29009152;   // 256x768 f32
static const size_t OFF_WHHT  = 29795584;   // 256x768 f32
static const size_t OFF_GX    = 30582016;   // 12x768 f32
static const size_t OFF_XBT   = 30618880;   // N*128 bf16
static const size_t OFF_P     = 35738880;   // N*256 bf16
static const size_t OFF_Q     = 45978880;   // N*256 bf16
// end ~56.2 MB

__device__ __forceinline__ float bf2f(unsigned short u) {
  return __uint_as_float(((unsigned int)u) << 16);
}
__device__ __forceinline__ unsigned short f2bf(float f) {
  unsigned int u = __float_as_uint(f);
  unsigned int r = (u + 0x7FFFu + ((u >> 16) & 1u)) >> 16;  // RNE
  return (unsigned short)r;
}
__device__ __forceinline__ float bflo(unsigned int u) { return __uint_as_float(u << 16); }
__device__ __forceinline__ float bfhi(unsigned int u) { return __uint_as_float(u & 0xFFFF0000u); }
__device__ __forceinline__ unsigned int packbf(float lo, float hi) {
  return (unsigned int)f2bf(lo) | ((unsigned int)f2bf(hi) << 16);
}
__device__ __forceinline__ float rec2nm(unsigned int rec) {
  return __half2float(__ushort_as_half((unsigned short)(rec >> 16)));
}

// ---------------- partial histogram: block (t, ech) owns edges [ech*EPC, +EPC) ----------------
__global__ __launch_bounds__(1024) void histp(const int* __restrict__ ei,
                                              const float* __restrict__ ea,
                                              float* __restrict__ degp,
                                              unsigned short* __restrict__ cnt16) {
  __shared__ float degs[N_];            // 80 KB
  __shared__ unsigned int cntp[N_ / 2]; // 40 KB
  const int t = blockIdx.x, ech = blockIdx.y;
  const int tid = threadIdx.x;
  for (int i = tid; i < N_; i += 1024) degs[i] = 0.f;
  for (int i = tid; i < N_ / 2; i += 1024) cntp[i] = 0u;
  __syncthreads();
  const int* col = ei + (size_t)t * 2 * E_ + E_ + ech * EPC;
  const float* wt = ea + (size_t)t * E_ + ech * EPC;
  for (int e = tid; e < EPC; e += 1024) {
    int c = col[e];
    atomicAdd(&degs[c], wt[e]);
    atomicAdd(&cntp[c >> 1], 1u << ((c & 1) * 16));
  }
  __syncthreads();
  float* dp = degp + ((size_t)t * ECH + ech) * N_;
  unsigned short* cp16 = cnt16 + ((size_t)t * ECH + ech) * N_;
  for (int i = tid; i < N_; i += 1024) {
    dp[i] = degs[i];
    cp16[i] = (unsigned short)((cntp[i >> 1] >> ((i & 1) * 16)) & 0xFFFFu);
  }
}

// ---------------- sum partials, scan -> colptr (per-t, node-major), dinv ----------------
__global__ __launch_bounds__(1024) void scanT(const unsigned short* __restrict__ cnt16,
                                              const float* __restrict__ degp,
                                              int* __restrict__ colptr,
                                              float* __restrict__ dinv) {
  const int t = blockIdx.x;
  __shared__ int s[1024];
  const int tid = threadIdx.x;
  int base = 0;
  for (int c0 = 0; c0 < N_; c0 += 1024) {
    int n = c0 + tid;
    int tot = 0;
    float dg = 0.f;
    if (n < N_) {
#pragma unroll
      for (int ch = 0; ch < ECH; ++ch) {
        tot += cnt16[((size_t)t * ECH + ch) * N_ + n];
        dg += degp[((size_t)t * ECH + ch) * N_ + n];
      }
    }
    s[tid] = tot;
    __syncthreads();
    for (int off = 1; off < 1024; off <<= 1) {
      int add = (tid >= off) ? s[tid - off] : 0;
      __syncthreads();
      s[tid] += add;
      __syncthreads();
    }
    if (n < N_) {
      colptr[t * (N_ + 1) + n] = base + s[tid] - tot;  // exclusive
      dinv[t * N_ + n] = rsqrtf(dg + 1.0f);
    }
    base += s[1023];
    __syncthreads();
  }
  if (tid == 0) colptr[t * (N_ + 1) + N_] = base;
}

// ---------------- bucketed CSR fill: LDS-staged scatter, coalesced write-out ----------------
__global__ __launch_bounds__(1024) void fillB(const int* __restrict__ ei,
                                              const float* __restrict__ ea,
                                              const int* __restrict__ colptr,
                                              const float* __restrict__ dinv,
                                              unsigned int* __restrict__ erec) {
  __shared__ unsigned int data[CAP];  // 96 KB staging
  __shared__ unsigned int offp[BN];   // 5 KB per-node next-slot (relative to bucket base)
  const int t = blockIdx.x, b = blockIdx.y;
  const int tid = threadIdx.x;
  const int nlo = b * BN;
  const int* cp = colptr + t * (N_ + 1);
  const int base = cp[nlo];
  const int bsize = cp[nlo + BN] - base;
  for (int i = tid; i < BN; i += 1024) offp[i] = (unsigned int)(cp[nlo + i] - base);
  __syncthreads();
  const int* rowp = ei + (size_t)t * 2 * E_;
  const int* colp = rowp + E_;
  const float* wt = ea + (size_t)t * E_;
  const float* dv = dinv + (size_t)t * N_;
  unsigned int* eg = erec + (size_t)t * E_ + base;
  for (int e = tid; e < E_; e += 1024) {
    int c = colp[e];
    unsigned int cl = (unsigned int)(c - nlo);
    if (cl < (unsigned int)BN) {
      int r = rowp[e];
      float nm = dv[r] * wt[e] * dv[c];
      unsigned int rec = (unsigned int)r |
                         ((unsigned int)__half_as_ushort(__float2half(nm)) << 16);
      unsigned int pos = atomicAdd(&offp[cl], 1u);
      if (pos < CAP) data[pos] = rec;
      else eg[pos] = rec;  // overflow slow path (unused at this distribution)
    }
  }
  __syncthreads();
  const int lim = bsize < CAP ? bsize : CAP;
  for (int i = tid; i < lim; i += 1024) eg[i] = data[i];
}

// ---------------- weight prep ----------------
__global__ __launch_bounds__(256) void prep_kernel(const float* __restrict__ W1,
                                                   const float* __restrict__ W2,
                                                   const float* __restrict__ Wih,
                                                   const float* __restrict__ Whh,
                                                   unsigned short* __restrict__ W1bT,
                                                   unsigned short* __restrict__ W2bT,
                                                   float* __restrict__ WihT,
                                                   float* __restrict__ WhhT) {
  int idx = blockIdx.x * 256 + threadIdx.x;
  if (idx < 32768) {
    int n = idx >> 7, k = idx & 127;
    W1bT[idx] = f2bf(W1[k * 256 + n]);
  } else if (idx < 98304) {
    int j = idx - 32768;
    int n = j >> 8, k = j & 255;
    W2bT[j] = f2bf(W2[k * 256 + n]);
  } else if (idx < 294912) {
    int j = idx - 98304;
    int k = j / 768, c = j - k * 768;
    WihT[j] = Wih[c * 256 + k];
  } else if (idx < 491520) {
    int j = idx - 294912;
    int k = j / 768, c = j - k * 768;
    WhhT[j] = Whh[c * 256 + k];
  }
}

// ---------------- cast x_t fp32 -> bf16 ----------------
__global__ __launch_bounds__(256) void castx_kernel(const float* __restrict__ x,
                                                    unsigned short* __restrict__ xb) {
  int idx = blockIdx.x * 256 + threadIdx.x;
  float4 v = ((const float4*)x)[idx];
  ushort4 o;
  o.x = f2bf(v.x); o.y = f2bf(v.y); o.z = f2bf(v.z); o.w = f2bf(v.w);
  ((ushort4*)xb)[idx] = o;
}

// ---------------- gather aggregate, single segment per node, 4B recs ----------------
__global__ __launch_bounds__(256) void agg128(const unsigned short* __restrict__ h,
                                              unsigned short* __restrict__ o,
                                              const unsigned int* __restrict__ erec,
                                              const int* __restrict__ cp,
                                              const float* __restrict__ dinv) {
  const int node = blockIdx.x * 4 + (threadIdx.x >> 6);
  const int lane = threadIdx.x & 63;
  float a0 = 0.f, a1 = 0.f;
  const int s0 = cp[node], s1 = cp[node + 1];
  for (int i = s0; i < s1; ++i) {
    const unsigned int rec = erec[i];
    const int r = rec & 0xFFFFu;
    const float nm = rec2nm(rec);
    unsigned int u = *(const unsigned int*)&h[(size_t)r * 128 + lane * 2];
    a0 = fmaf(nm, bflo(u), a0);
    a1 = fmaf(nm, bfhi(u), a1);
  }
  const float di = dinv[node];
  const float sw = di * di;
  unsigned int us = *(const unsigned int*)&h[(size_t)node * 128 + lane * 2];
  a0 = fmaf(sw, bflo(us), a0);
  a1 = fmaf(sw, bfhi(us), a1);
  *(unsigned int*)&o[(size_t)node * 128 + lane * 2] = packbf(a0, a1);
}

__global__ __launch_bounds__(256) void agg256(const unsigned short* __restrict__ h,
                                              unsigned short* __restrict__ o,
                                              const unsigned int* __restrict__ erec,
                                              const int* __restrict__ cp,
                                              const float* __restrict__ dinv) {
  const int node = blockIdx.x * 4 + (threadIdx.x >> 6);
  const int lane = threadIdx.x & 63;
  float a0 = 0.f, a1 = 0.f, a2 = 0.f, a3 = 0.f;
  const int s0 = cp[node], s1 = cp[node + 1];
  for (int i = s0; i < s1; ++i) {
    const unsigned int rec = erec[i];
    const int r = rec & 0xFFFFu;
    const float nm = rec2nm(rec);
    uint2 u = *(const uint2*)&h[(size_t)r * 256 + lane * 4];
    a0 = fmaf(nm, bflo(u.x), a0);
    a1 = fmaf(nm, bfhi(u.x), a1);
    a2 = fmaf(nm, bflo(u.y), a2);
    a3 = fmaf(nm, bfhi(u.y), a3);
  }
  const float di = dinv[node];
  const float sw = di * di;
  uint2 us = *(const uint2*)&h[(size_t)node * 256 + lane * 4];
  a0 = fmaf(sw, bflo(us.x), a0);
  a1 = fmaf(sw, bfhi(us.x), a1);
  a2 = fmaf(sw, bflo(us.y), a2);
  a3 = fmaf(sw, bfhi(us.y), a3);
  uint2 ov;
  ov.x = packbf(a0, a1);
  ov.y = packbf(a2, a3);
  *(uint2*)&o[(size_t)node * 256 + lane * 4] = ov;
}

// ---------------- bf16 MFMA GEMM; MEAN: skip C store, accumulate column mean ----------------
// block: 64 rows x 128 cols, 4 waves (wave w: rows (w>>1)*32, cols (w&1)*64)
template <int K, bool MEAN>
__global__ __launch_bounds__(256) void gemm_bf16(const unsigned short* __restrict__ A,
                                                 const unsigned short* __restrict__ BT,  // [256][K]
                                                 const float* __restrict__ bias,
                                                 unsigned short* __restrict__ C,
                                                 float* __restrict__ embp, int M) {
  constexpr int LD = K + 8;
  __shared__ unsigned short As[64 * LD];
  __shared__ float cs[128];
  const int tid = threadIdx.x;
  const int bm = blockIdx.x * 64;
  const int bn = blockIdx.y * 128;
  if (MEAN && tid < 128) cs[tid] = 0.f;
  {
    constexpr int CPR = K / 8;
    constexpr int CH = 64 * CPR / 256;
#pragma unroll
    for (int i = 0; i < CH; ++i) {
      int chunk = tid + i * 256;
      int r = chunk / CPR;
      int ck = (chunk - r * CPR) * 8;
      int row = bm + r;
      if (row >= M) row = M - 1;
      *(bf16x8*)&As[r * LD + ck] = *(const bf16x8*)&A[(size_t)row * K + ck];
    }
  }
  __syncthreads();
  const int w = tid >> 6, l = tid & 63;
  const int l16 = l & 15, lk = l >> 4;
  const int rbase = (w >> 1) * 32;
  const int colbase = bn + (w & 1) * 64;
  f32x4 acc[2][4] = {};
  for (int ks = 0; ks < K; ks += 32) {
    bf16x8 a[2], b[4];
#pragma unroll
    for (int m = 0; m < 2; ++m)
      a[m] = *(const bf16x8*)&As[(rbase + m * 16 + l16) * LD + ks + lk * 8];
#pragma unroll
    for (int n = 0; n < 4; ++n)
      b[n] = *(const bf16x8*)&BT[(size_t)(colbase + n * 16 + l16) * K + ks + lk * 8];
#pragma unroll
    for (int m = 0; m < 2; ++m)
#pragma unroll
      for (int n = 0; n < 4; ++n)
        acc[m][n] = __builtin_amdgcn_mfma_f32_16x16x32_bf16(a[m], b[n], acc[m][n], 0, 0, 0);
  }
#pragma unroll
  for (int n = 0; n < 4; ++n) {
    int col = colbase + n * 16 + l16;
    float bv = bias[col];
    float psum = 0.f;
#pragma unroll
    for (int m = 0; m < 2; ++m) {
      int row0 = bm + rbase + m * 16 + lk * 4;
#pragma unroll
      for (int r = 0; r < 4; ++r) {
        int row = row0 + r;
        if (row < M) {
          float v = fmaxf(acc[m][n][r] + bv, 0.f);
          if (MEAN) psum += v;
          else C[(size_t)row * 256 + col] = f2bf(v);
        }
      }
    }
    if (MEAN) atomicAdd(&cs[col - bn], psum);
  }
  if (MEAN) {
    __syncthreads();
    if (tid < 128) atomicAdd(&embp[bn + tid], cs[tid] * (1.0f / N_));
  }
}

// ---------------- GX[t] = Wih @ emb_t + bih ----------------
__global__ __launch_bounds__(768) void gx_kernel(const float* __restrict__ emb,
                                                 const float* __restrict__ WihT,  // [256][768]
                                                 const float* __restrict__ bih,
                                                 float* __restrict__ GX) {
  const int t = blockIdx.x;
  const int tid = threadIdx.x;
  __shared__ float se[256];
  if (tid < 256) se[tid] = emb[t * 256 + tid];
  __syncthreads();
  float p0 = 0.f, p1 = 0.f, p2 = 0.f, p3 = 0.f;
#pragma unroll 8
  for (int k = 0; k < 256; k += 4) {
    p0 = fmaf(WihT[(size_t)(k + 0) * 768 + tid], se[k + 0], p0);
    p1 = fmaf(WihT[(size_t)(k + 1) * 768 + tid], se[k + 1], p1);
    p2 = fmaf(WihT[(size_t)(k + 2) * 768 + tid], se[k + 2], p2);
    p3 = fmaf(WihT[(size_t)(k + 3) * 768 + tid], se[k + 3], p3);
  }
  GX[t * 768 + tid] = (p0 + p1) + (p2 + p3) + bih[tid];
}

// ---------------- sequential GRU + final linear ----------------
__global__ __launch_bounds__(768) void gru2_kernel(const float* __restrict__ GX,
                                                   const float* __restrict__ WhhT,  // [256][768]
                                                   const float* __restrict__ bhh,
                                                   const float* __restrict__ Wc,
                                                   const float* __restrict__ bc,
                                                   float* __restrict__ out) {
  __shared__ float sh[256];
  __shared__ float sgh[768];
  const int tid = threadIdx.x;
  if (tid < 256) sh[tid] = 0.f;
  __syncthreads();
  for (int t = 0; t < T_; ++t) {
    float p0 = 0.f, p1 = 0.f, p2 = 0.f, p3 = 0.f;
#pragma unroll 8
    for (int k = 0; k < 256; k += 4) {
      p0 = fmaf(WhhT[(size_t)(k + 0) * 768 + tid], sh[k + 0], p0);
      p1 = fmaf(WhhT[(size_t)(k + 1) * 768 + tid], sh[k + 1], p1);
      p2 = fmaf(WhhT[(size_t)(k + 2) * 768 + tid], sh[k + 2], p2);
      p3 = fmaf(WhhT[(size_t)(k + 3) * 768 + tid], sh[k + 3], p3);
    }
    sgh[tid] = (p0 + p1) + (p2 + p3) + bhh[tid];
    __syncthreads();
    if (tid < 256) {
      const float* gx = &GX[t * 768];
      float r = 1.f / (1.f + __expf(-(gx[tid] + sgh[tid])));
      float z = 1.f / (1.f + __expf(-(gx[256 + tid] + sgh[256 + tid])));
      float n = tanhf(gx[512 + tid] + r * sgh[512 + tid]);
      sh[tid] = (1.f - z) * n + z * sh[tid];
    }
    __syncthreads();
  }
  const int wv = tid >> 6, lane = tid & 63;
  if (wv < C_) {
    float p = 0.f;
#pragma unroll
    for (int i = 0; i < 4; ++i) {
      int j = lane + 64 * i;
      p += sh[j] * Wc[(size_t)j * C_ + wv];
    }
    for (int off = 32; off > 0; off >>= 1) p += __shfl_down(p, off);
    if (lane == 0) out[wv] = p + bc[wv];
  }
}

extern "C" void kernel_launch(void* const* d_in, const int* in_sizes, int n_in,
                              void* d_out, int out_size, void* d_ws, size_t ws_size,
                              hipStream_t stream) {
  const float* x   = (const float*)d_in[0];
  const int*   ei  = (const int*)d_in[1];
  const float* ea  = (const float*)d_in[2];
  const float* W1  = (const float*)d_in[3];
  const float* b1  = (const float*)d_in[4];
  const float* W2  = (const float*)d_in[5];
  const float* b2  = (const float*)d_in[6];
  const float* Wih = (const float*)d_in[7];
  const float* Whh = (const float*)d_in[8];
  const float* bih = (const float*)d_in[9];
  const float* bhh = (const float*)d_in[10];
  const float* Wc  = (const float*)d_in[11];
  const float* bc  = (const float*)d_in[12];
  float* out = (float*)d_out;

  char* w = (char*)d_ws;
  float* emb   = (float*)(w + OFF_EMB);
  float* dinv  = (float*)(w + OFF_DINV);
  int*   cp    = (int*)(w + OFF_CP);
  float* degp  = (float*)(w + OFF_DEGP);
  unsigned short* cnt16 = (unsigned short*)(w + OFF_CNT16);
  unsigned int* erec = (unsigned int*)(w + OFF_EREC);
  unsigned short* W1bT = (unsigned short*)(w + OFF_W1BT);
  unsigned short* W2bT = (unsigned short*)(w + OFF_W2BT);
  float* WihT  = (float*)(w + OFF_WIHT);
  float* WhhT  = (float*)(w + OFF_WHHT);
  float* GX    = (float*)(w + OFF_GX);
  unsigned short* xbt = (unsigned short*)(w + OFF_XBT);
  unsigned short* P   = (unsigned short*)(w + OFF_P);
  unsigned short* Q   = (unsigned short*)(w + OFF_Q);

  hipMemsetAsync(d_ws, 0, ZERO_BYTES, stream);

  prep_kernel<<<1920, 256, 0, stream>>>(W1, W2, Wih, Whh, W1bT, W2bT, WihT, WhhT);

  dim3 hist_grid(T_, ECH);
  histp<<<hist_grid, 1024, 0, stream>>>(ei, ea, degp, cnt16);
  scanT<<<T_, 1024, 0, stream>>>(cnt16, degp, cp, dinv);
  dim3 fill_grid(T_, NB);
  fillB<<<fill_grid, 1024, 0, stream>>>(ei, ea, cp, dinv, erec);

  dim3 gemm_grid((N_ + 63) / 64, 2);
  for (int t = 0; t < T_; ++t) {
    const int* cpt = cp + (size_t)t * (N_ + 1);
    const unsigned int* ert = erec + (size_t)t * E_;
    const float* dvt = dinv + (size_t)t * N_;
    castx_kernel<<<2500, 256, 0, stream>>>(x + (size_t)t * N_ * FIN_, xbt);
    agg128<<<N_ / 4, 256, 0, stream>>>(xbt, P, ert, cpt, dvt);
    gemm_bf16<FIN_, false><<<gemm_grid, 256, 0, stream>>>(P, W1bT, b1, Q, nullptr, N_);
    agg256<<<N_ / 4, 256, 0, stream>>>(Q, P, ert, cpt, dvt);
    gemm_bf16<H_, true><<<gemm_grid, 256, 0, stream>>>(P, W2bT, b2, nullptr, emb + t * H_, N_);
  }
  gx_kernel<<<T_, 768, 0, stream>>>(emb, WihT, bih, GX);
  gru2_kernel<<<1, 768, 0, stream>>>(GX, WhhT, bhh, Wc, bc, out);
}

// Round 9
// 1591.699 us; speedup vs baseline: 1.5650x; 1.1607x over previous
//
#include <hip/hip_runtime.h>
#include <hip/hip_fp16.h>
#include <math.h>

#define T_ 12
#define N_ 20000
#define E_ 320000
#define FIN_ 128
#define H_ 256
#define G_ 256
#define C_ 10
#define ECH 8
#define EPC (E_ / ECH)
#define NB 32
#define BN_ (N_ / NB)   // 625 nodes per bucket
#define CAPB 11264      // LDS staging recs (mean 10000, +12 sigma); overflow -> direct store

typedef __attribute__((ext_vector_type(8))) short bf16x8;
typedef __attribute__((ext_vector_type(4))) float f32x4;

// ---------------- workspace layout (bytes) ----------------
static const size_t OFF_EMB   = 0;          // T*256 f32 (zeroed each launch)
static const size_t ZERO_BYTES= 12288;
static const size_t OFF_DINV  = 12288;      // T*N f32
static const size_t OFF_CP    = 972288;     // T*(N+1) i32
static const size_t OFF_DEGP  = 1932544;    // T*ECH*N f32
static const size_t OFF_CNT16 = 9612544;    // T*ECH*N u16
static const size_t OFF_C16   = 13452544;   // T*E u16 packed cols
static const size_t OFF_RW    = 21132544;   // T*E u32 (row u16 | wt f16)
static const size_t OFF_EREC  = 36492544;   // T*E u32 CSR recs (row u16 | nm f16)
static const size_t OFF_W1BT  = 51852544;   // 256x128 bf16
static const size_t OFF_W2BT  = 51918080;   // 256x256 bf16
static const size_t OFF_WIHT  = 52049152;   // 256x768 f32
static const size_t OFF_WHHT  = 52835584;   // 256x768 f32
static const size_t OFF_GX    = 53622016;   // 12x768 f32
static const size_t OFF_XBT   = 53658880;   // bf16 x tiles (per-t or all-t)
// batched mode:
static const size_t BAT_P     = 115098880;  // 12*N*256 bf16
static const size_t BAT_Q     = 237978880;  // 12*N*256 bf16
static const size_t NEED_BATCH= 360858880;
// fallback mode (proven <=79.3 MB footprint):
static const size_t FB_P      = 58778880;   // N*256 bf16
static const size_t FB_Q      = 69018880;   // N*256 bf16

__device__ __forceinline__ float bf2f(unsigned short u) {
  return __uint_as_float(((unsigned int)u) << 16);
}
__device__ __forceinline__ unsigned short f2bf(float f) {
  unsigned int u = __float_as_uint(f);
  unsigned int r = (u + 0x7FFFu + ((u >> 16) & 1u)) >> 16;  // RNE
  return (unsigned short)r;
}
__device__ __forceinline__ float bflo(unsigned int u) { return __uint_as_float(u << 16); }
__device__ __forceinline__ float bfhi(unsigned int u) { return __uint_as_float(u & 0xFFFF0000u); }
__device__ __forceinline__ unsigned int packbf(float lo, float hi) {
  return (unsigned int)f2bf(lo) | ((unsigned int)f2bf(hi) << 16);
}
__device__ __forceinline__ float rec2nm(unsigned int rec) {
  return __half2float(__ushort_as_half((unsigned short)(rec >> 16)));
}

// ---------------- partial histogram + stream packing ----------------
__global__ __launch_bounds__(1024) void histp(const int* __restrict__ ei,
                                              const float* __restrict__ ea,
                                              float* __restrict__ degp,
                                              unsigned short* __restrict__ cnt16,
                                              unsigned short* __restrict__ c16,
                                              unsigned int* __restrict__ rw) {
  __shared__ float degs[N_];            // 80 KB
  __shared__ unsigned int cntp[N_ / 2]; // 40 KB
  const int t = blockIdx.x, ech = blockIdx.y;
  const int tid = threadIdx.x;
  for (int i = tid; i < N_; i += 1024) degs[i] = 0.f;
  for (int i = tid; i < N_ / 2; i += 1024) cntp[i] = 0u;
  __syncthreads();
  const int eoff = ech * EPC;
  const int* rowp = ei + (size_t)t * 2 * E_ + eoff;
  const int* colp = rowp + E_;
  const float* wt = ea + (size_t)t * E_ + eoff;
  unsigned short* c16t = c16 + (size_t)t * E_ + eoff;
  unsigned int* rwt = rw + (size_t)t * E_ + eoff;
  for (int e = tid; e < EPC; e += 1024) {
    int c = colp[e];
    float wv = wt[e];
    atomicAdd(&degs[c], wv);
    atomicAdd(&cntp[c >> 1], 1u << ((c & 1) * 16));
    c16t[e] = (unsigned short)c;
    rwt[e] = (unsigned int)rowp[e] |
             ((unsigned int)__half_as_ushort(__float2half(wv)) << 16);
  }
  __syncthreads();
  float* dp = degp + ((size_t)t * ECH + ech) * N_;
  unsigned short* cp16 = cnt16 + ((size_t)t * ECH + ech) * N_;
  for (int i = tid; i < N_; i += 1024) {
    dp[i] = degs[i];
    cp16[i] = (unsigned short)((cntp[i >> 1] >> ((i & 1) * 16)) & 0xFFFFu);
  }
}

// ---------------- sum partials, scan -> colptr, dinv ----------------
__global__ __launch_bounds__(1024) void scanT(const unsigned short* __restrict__ cnt16,
                                              const float* __restrict__ degp,
                                              int* __restrict__ colptr,
                                              float* __restrict__ dinv) {
  const int t = blockIdx.x;
  __shared__ int s[1024];
  const int tid = threadIdx.x;
  int base = 0;
  for (int c0 = 0; c0 < N_; c0 += 1024) {
    int n = c0 + tid;
    int tot = 0;
    float dg = 0.f;
    if (n < N_) {
#pragma unroll
      for (int ch = 0; ch < ECH; ++ch) {
        tot += cnt16[((size_t)t * ECH + ch) * N_ + n];
        dg += degp[((size_t)t * ECH + ch) * N_ + n];
      }
    }
    s[tid] = tot;
    __syncthreads();
    for (int off = 1; off < 1024; off <<= 1) {
      int add = (tid >= off) ? s[tid - off] : 0;
      __syncthreads();
      s[tid] += add;
      __syncthreads();
    }
    if (n < N_) {
      colptr[t * (N_ + 1) + n] = base + s[tid] - tot;
      dinv[t * N_ + n] = rsqrtf(dg + 1.0f);
    }
    base += s[1023];
    __syncthreads();
  }
  if (tid == 0) colptr[t * (N_ + 1) + N_] = base;
}

// ---------------- bucketed CSR fill: 32 buckets, 512 thr, 50 KB LDS ----------------
__global__ __launch_bounds__(512) void fillB(const unsigned short* __restrict__ c16,
                                             const unsigned int* __restrict__ rw,
                                             const int* __restrict__ colptr,
                                             const float* __restrict__ dinv,
                                             unsigned int* __restrict__ erec) {
  __shared__ unsigned int data[CAPB];  // 44 KB staging
  __shared__ unsigned int offp[BN_];   // 2.5 KB
  __shared__ float dvb[BN_];           // 2.5 KB
  const int t = blockIdx.x, b = blockIdx.y;
  const int tid = threadIdx.x;
  const int nlo = b * BN_;
  const int* cp = colptr + t * (N_ + 1);
  const int base = cp[nlo];
  const int bsize = cp[nlo + BN_] - base;
  const float* dv = dinv + (size_t)t * N_;
  for (int i = tid; i < BN_; i += 512) {
    offp[i] = (unsigned int)(cp[nlo + i] - base);
    dvb[i] = dv[nlo + i];
  }
  __syncthreads();
  const unsigned short* ct = c16 + (size_t)t * E_;
  const unsigned int* rwt = rw + (size_t)t * E_;
  unsigned int* eg = erec + (size_t)t * E_ + base;
  for (int e = tid; e < E_; e += 512) {
    unsigned int cl = (unsigned int)ct[e] - (unsigned int)nlo;
    if (cl < (unsigned int)BN_) {
      unsigned int r8 = rwt[e];
      int r = r8 & 0xFFFFu;
      float wv = __half2float(__ushort_as_half((unsigned short)(r8 >> 16)));
      float nm = dv[r] * wv * dvb[cl];
      unsigned int rec = (unsigned int)r |
                         ((unsigned int)__half_as_ushort(__float2half(nm)) << 16);
      unsigned int pos = atomicAdd(&offp[cl], 1u);
      if (pos < CAPB) data[pos] = rec;
      else eg[pos] = rec;
    }
  }
  __syncthreads();
  const int lim = bsize < CAPB ? bsize : CAPB;
  for (int i = tid; i < lim; i += 512) eg[i] = data[i];
}

// ---------------- weight prep ----------------
__global__ __launch_bounds__(256) void prep_kernel(const float* __restrict__ W1,
                                                   const float* __restrict__ W2,
                                                   const float* __restrict__ Wih,
                                                   const float* __restrict__ Whh,
                                                   unsigned short* __restrict__ W1bT,
                                                   unsigned short* __restrict__ W2bT,
                                                   float* __restrict__ WihT,
                                                   float* __restrict__ WhhT) {
  int idx = blockIdx.x * 256 + threadIdx.x;
  if (idx < 32768) {
    int n = idx >> 7, k = idx & 127;
    W1bT[idx] = f2bf(W1[k * 256 + n]);
  } else if (idx < 98304) {
    int j = idx - 32768;
    int n = j >> 8, k = j & 255;
    W2bT[j] = f2bf(W2[k * 256 + n]);
  } else if (idx < 294912) {
    int j = idx - 98304;
    int k = j / 768, c = j - k * 768;
    WihT[j] = Wih[c * 256 + k];
  } else if (idx < 491520) {
    int j = idx - 294912;
    int k = j / 768, c = j - k * 768;
    WhhT[j] = Whh[c * 256 + k];
  }
}

// ---------------- cast x_t fp32 -> bf16 (y = local t) ----------------
__global__ __launch_bounds__(256) void castx_kernel(const float* __restrict__ x,
                                                    unsigned short* __restrict__ xb,
                                                    int t_base) {
  const int tl = blockIdx.y;
  const int t = t_base + tl;
  const size_t q = (size_t)blockIdx.x * 256 + threadIdx.x;  // float4 units
  float4 v = ((const float4*)x)[(size_t)t * (N_ * FIN_ / 4) + q];
  ushort4 o;
  o.x = f2bf(v.x); o.y = f2bf(v.y); o.z = f2bf(v.z); o.w = f2bf(v.w);
  ((ushort4*)xb)[(size_t)tl * (N_ * FIN_ / 4) + q] = o;
}

// ---------------- gather aggregate (1D grid nt*5000, XCD-swizzled when batched) ----------------
__device__ __forceinline__ void agg_decode(int nt, int t_base, int& t, int& tl, int& node) {
  int bid = blockIdx.x;
  int L = bid;
  if (nt > 1) {
    int chunk = (int)(gridDim.x >> 3);
    L = (bid & 7) * chunk + (bid >> 3);
  }
  tl = L / 5000;
  node = (L - tl * 5000) * 4 + ((int)threadIdx.x >> 6);
  t = t_base + tl;
}

__global__ __launch_bounds__(256) void agg128(const unsigned short* __restrict__ h,
                                              unsigned short* __restrict__ o,
                                              const unsigned int* __restrict__ erec,
                                              const int* __restrict__ colptr,
                                              const float* __restrict__ dinv,
                                              int t_base, int nt) {
  int t, tl, node;
  agg_decode(nt, t_base, t, tl, node);
  const int lane = threadIdx.x & 63;
  const unsigned int* ert = erec + (size_t)t * E_;
  const int* cp = colptr + t * (N_ + 1);
  const unsigned short* ht = h + (size_t)tl * N_ * 128;
  float a0 = 0.f, a1 = 0.f;
  const int s0 = cp[node], s1 = cp[node + 1];
  for (int i = s0; i < s1; ++i) {
    const unsigned int rec = ert[i];
    const int r = rec & 0xFFFFu;
    const float nm = rec2nm(rec);
    unsigned int u = *(const unsigned int*)&ht[(size_t)r * 128 + lane * 2];
    a0 = fmaf(nm, bflo(u), a0);
    a1 = fmaf(nm, bfhi(u), a1);
  }
  const float di = dinv[(size_t)t * N_ + node];
  const float sw = di * di;
  unsigned int us = *(const unsigned int*)&ht[(size_t)node * 128 + lane * 2];
  a0 = fmaf(sw, bflo(us), a0);
  a1 = fmaf(sw, bfhi(us), a1);
  *(unsigned int*)&o[((size_t)tl * N_ + node) * 128 + lane * 2] = packbf(a0, a1);
}

__global__ __launch_bounds__(256) void agg256(const unsigned short* __restrict__ h,
                                              unsigned short* __restrict__ o,
                                              const unsigned int* __restrict__ erec,
                                              const int* __restrict__ colptr,
                                              const float* __restrict__ dinv,
                                              int t_base, int nt) {
  int t, tl, node;
  agg_decode(nt, t_base, t, tl, node);
  const int lane = threadIdx.x & 63;
  const unsigned int* ert = erec + (size_t)t * E_;
  const int* cp = colptr + t * (N_ + 1);
  const unsigned short* ht = h + (size_t)tl * N_ * 256;
  float a0 = 0.f, a1 = 0.f, a2 = 0.f, a3 = 0.f;
  const int s0 = cp[node], s1 = cp[node + 1];
  for (int i = s0; i < s1; ++i) {
    const unsigned int rec = ert[i];
    const int r = rec & 0xFFFFu;
    const float nm = rec2nm(rec);
    uint2 u = *(const uint2*)&ht[(size_t)r * 256 + lane * 4];
    a0 = fmaf(nm, bflo(u.x), a0);
    a1 = fmaf(nm, bfhi(u.x), a1);
    a2 = fmaf(nm, bflo(u.y), a2);
    a3 = fmaf(nm, bfhi(u.y), a3);
  }
  const float di = dinv[(size_t)t * N_ + node];
  const float sw = di * di;
  uint2 us = *(const uint2*)&ht[(size_t)node * 256 + lane * 4];
  a0 = fmaf(sw, bflo(us.x), a0);
  a1 = fmaf(sw, bfhi(us.x), a1);
  a2 = fmaf(sw, bflo(us.y), a2);
  a3 = fmaf(sw, bfhi(us.y), a3);
  uint2 ov;
  ov.x = packbf(a0, a1);
  ov.y = packbf(a2, a3);
  *(uint2*)&o[((size_t)tl * N_ + node) * 256 + lane * 4] = ov;
}

// ---------------- bf16 MFMA GEMM (z = local t); MEAN fuses column-mean ----------------
template <int K, bool MEAN>
__global__ __launch_bounds__(256) void gemm_bf16(const unsigned short* __restrict__ A,
                                                 const unsigned short* __restrict__ BT,  // [256][K]
                                                 const float* __restrict__ bias,
                                                 unsigned short* __restrict__ C,
                                                 float* __restrict__ embp,
                                                 int t_base) {
  constexpr int LD = K + 8;
  __shared__ unsigned short As[64 * LD];
  __shared__ float cs[128];
  const int tid = threadIdx.x;
  const int tl = blockIdx.z;
  const int bm = blockIdx.x * 64;
  const int bn = blockIdx.y * 128;
  const unsigned short* At = A + (size_t)tl * N_ * K;
  if (MEAN && tid < 128) cs[tid] = 0.f;
  {
    constexpr int CPR = K / 8;
    constexpr int CH = 64 * CPR / 256;
#pragma unroll
    for (int i = 0; i < CH; ++i) {
      int chunk = tid + i * 256;
      int r = chunk / CPR;
      int ck = (chunk - r * CPR) * 8;
      int row = bm + r;
      if (row >= N_) row = N_ - 1;
      *(bf16x8*)&As[r * LD + ck] = *(const bf16x8*)&At[(size_t)row * K + ck];
    }
  }
  __syncthreads();
  const int w = tid >> 6, l = tid & 63;
  const int l16 = l & 15, lk = l >> 4;
  const int rbase = (w >> 1) * 32;
  const int colbase = bn + (w & 1) * 64;
  f32x4 acc[2][4] = {};
  for (int ks = 0; ks < K; ks += 32) {
    bf16x8 a[2], b[4];
#pragma unroll
    for (int m = 0; m < 2; ++m)
      a[m] = *(const bf16x8*)&As[(rbase + m * 16 + l16) * LD + ks + lk * 8];
#pragma unroll
    for (int n = 0; n < 4; ++n)
      b[n] = *(const bf16x8*)&BT[(size_t)(colbase + n * 16 + l16) * K + ks + lk * 8];
#pragma unroll
    for (int m = 0; m < 2; ++m)
#pragma unroll
      for (int n = 0; n < 4; ++n)
        acc[m][n] = __builtin_amdgcn_mfma_f32_16x16x32_bf16(a[m], b[n], acc[m][n], 0, 0, 0);
  }
#pragma unroll
  for (int n = 0; n < 4; ++n) {
    int col = colbase + n * 16 + l16;
    float bv = bias[col];
    float psum = 0.f;
#pragma unroll
    for (int m = 0; m < 2; ++m) {
      int row0 = bm + rbase + m * 16 + lk * 4;
#pragma unroll
      for (int r = 0; r < 4; ++r) {
        int row = row0 + r;
        if (row < N_) {
          float v = fmaxf(acc[m][n][r] + bv, 0.f);
          if (MEAN) psum += v;
          else C[((size_t)tl * N_ + row) * 256 + col] = f2bf(v);
        }
      }
    }
    if (MEAN) atomicAdd(&cs[col - bn], psum);
  }
  if (MEAN) {
    __syncthreads();
    if (tid < 128)
      atomicAdd(&embp[(t_base + tl) * 256 + bn + tid], cs[tid] * (1.0f / N_));
  }
}

// ---------------- GX[t] = Wih @ emb_t + bih ----------------
__global__ __launch_bounds__(768) void gx_kernel(const float* __restrict__ emb,
                                                 const float* __restrict__ WihT,
                                                 const float* __restrict__ bih,
                                                 float* __restrict__ GX) {
  const int t = blockIdx.x;
  const int tid = threadIdx.x;
  __shared__ float se[256];
  if (tid < 256) se[tid] = emb[t * 256 + tid];
  __syncthreads();
  float p0 = 0.f, p1 = 0.f, p2 = 0.f, p3 = 0.f;
#pragma unroll 8
  for (int k = 0; k < 256; k += 4) {
    p0 = fmaf(WihT[(size_t)(k + 0) * 768 + tid], se[k + 0], p0);
    p1 = fmaf(WihT[(size_t)(k + 1) * 768 + tid], se[k + 1], p1);
    p2 = fmaf(WihT[(size_t)(k + 2) * 768 + tid], se[k + 2], p2);
    p3 = fmaf(WihT[(size_t)(k + 3) * 768 + tid], se[k + 3], p3);
  }
  GX[t * 768 + tid] = (p0 + p1) + (p2 + p3) + bih[tid];
}

// ---------------- sequential GRU + final linear ----------------
__global__ __launch_bounds__(768) void gru2_kernel(const float* __restrict__ GX,
                                                   const float* __restrict__ WhhT,
                                                   const float* __restrict__ bhh,
                                                   const float* __restrict__ Wc,
                                                   const float* __restrict__ bc,
                                                   float* __restrict__ out) {
  __shared__ float sh[256];
  __shared__ float sgh[768];
  const int tid = threadIdx.x;
  if (tid < 256) sh[tid] = 0.f;
  __syncthreads();
  for (int t = 0; t < T_; ++t) {
    float p0 = 0.f, p1 = 0.f, p2 = 0.f, p3 = 0.f;
#pragma unroll 8
    for (int k = 0; k < 256; k += 4) {
      p0 = fmaf(WhhT[(size_t)(k + 0) * 768 + tid], sh[k + 0], p0);
      p1 = fmaf(WhhT[(size_t)(k + 1) * 768 + tid], sh[k + 1], p1);
      p2 = fmaf(WhhT[(size_t)(k + 2) * 768 + tid], sh[k + 2], p2);
      p3 = fmaf(WhhT[(size_t)(k + 3) * 768 + tid], sh[k + 3], p3);
    }
    sgh[tid] = (p0 + p1) + (p2 + p3) + bhh[tid];
    __syncthreads();
    if (tid < 256) {
      const float* gx = &GX[t * 768];
      float r = 1.f / (1.f + __expf(-(gx[tid] + sgh[tid])));
      float z = 1.f / (1.f + __expf(-(gx[256 + tid] + sgh[256 + tid])));
      float n = tanhf(gx[512 + tid] + r * sgh[512 + tid]);
      sh[tid] = (1.f - z) * n + z * sh[tid];
    }
    __syncthreads();
  }
  const int wv = tid >> 6, lane = tid & 63;
  if (wv < C_) {
    float p = 0.f;
#pragma unroll
    for (int i = 0; i < 4; ++i) {
      int j = lane + 64 * i;
      p += sh[j] * Wc[(size_t)j * C_ + wv];
    }
    for (int off = 32; off > 0; off >>= 1) p += __shfl_down(p, off);
    if (lane == 0) out[wv] = p + bc[wv];
  }
}

extern "C" void kernel_launch(void* const* d_in, const int* in_sizes, int n_in,
                              void* d_out, int out_size, void* d_ws, size_t ws_size,
                              hipStream_t stream) {
  const float* x   = (const float*)d_in[0];
  const int*   ei  = (const int*)d_in[1];
  const float* ea  = (const float*)d_in[2];
  const float* W1  = (const float*)d_in[3];
  const float* b1  = (const float*)d_in[4];
  const float* W2  = (const float*)d_in[5];
  const float* b2  = (const float*)d_in[6];
  const float* Wih = (const float*)d_in[7];
  const float* Whh = (const float*)d_in[8];
  const float* bih = (const float*)d_in[9];
  const float* bhh = (const float*)d_in[10];
  const float* Wc  = (const float*)d_in[11];
  const float* bc  = (const float*)d_in[12];
  float* out = (float*)d_out;

  char* w = (char*)d_ws;
  float* emb   = (float*)(w + OFF_EMB);
  float* dinv  = (float*)(w + OFF_DINV);
  int*   cp    = (int*)(w + OFF_CP);
  float* degp  = (float*)(w + OFF_DEGP);
  unsigned short* cnt16 = (unsigned short*)(w + OFF_CNT16);
  unsigned short* c16   = (unsigned short*)(w + OFF_C16);
  unsigned int* rw   = (unsigned int*)(w + OFF_RW);
  unsigned int* erec = (unsigned int*)(w + OFF_EREC);
  unsigned short* W1bT = (unsigned short*)(w + OFF_W1BT);
  unsigned short* W2bT = (unsigned short*)(w + OFF_W2BT);
  float* WihT  = (float*)(w + OFF_WIHT);
  float* WhhT  = (float*)(w + OFF_WHHT);
  float* GX    = (float*)(w + OFF_GX);
  unsigned short* xbt = (unsigned short*)(w + OFF_XBT);

  const bool batched = ws_size >= NEED_BATCH;
  unsigned short* P = (unsigned short*)(w + (batched ? BAT_P : FB_P));
  unsigned short* Q = (unsigned short*)(w + (batched ? BAT_Q : FB_Q));

  hipMemsetAsync(d_ws, 0, ZERO_BYTES, stream);

  prep_kernel<<<1920, 256, 0, stream>>>(W1, W2, Wih, Whh, W1bT, W2bT, WihT, WhhT);

  dim3 hist_grid(T_, ECH);
  histp<<<hist_grid, 1024, 0, stream>>>(ei, ea, degp, cnt16, c16, rw);
  scanT<<<T_, 1024, 0, stream>>>(cnt16, degp, cp, dinv);
  dim3 fill_grid(T_, NB);
  fillB<<<fill_grid, 512, 0, stream>>>(c16, rw, cp, dinv, erec);

  if (batched) {
    castx_kernel<<<dim3(2500, T_), 256, 0, stream>>>(x, xbt, 0);
    agg128<<<T_ * 5000, 256, 0, stream>>>(xbt, P, erec, cp, dinv, 0, T_);
    gemm_bf16<FIN_, false><<<dim3(313, 2, T_), 256, 0, stream>>>(P, W1bT, b1, Q, nullptr, 0);
    agg256<<<T_ * 5000, 256, 0, stream>>>(Q, P, erec, cp, dinv, 0, T_);
    gemm_bf16<H_, true><<<dim3(313, 2, T_), 256, 0, stream>>>(P, W2bT, b2, nullptr, emb, 0);
  } else {
    for (int t = 0; t < T_; ++t) {
      castx_kernel<<<dim3(2500, 1), 256, 0, stream>>>(x, xbt, t);
      agg128<<<5000, 256, 0, stream>>>(xbt, P, erec, cp, dinv, t, 1);
      gemm_bf16<FIN_, false><<<dim3(313, 2, 1), 256, 0, stream>>>(P, W1bT, b1, Q, nullptr, t);
      agg256<<<5000, 256, 0, stream>>>(Q, P, erec, cp, dinv, t, 1);
      gemm_bf16<H_, true><<<dim3(313, 2, 1), 256, 0, stream>>>(P, W2bT, b2, nullptr, emb, t);
    }
  }
  gx_kernel<<<T_, 768, 0, stream>>>(emb, WihT, bih, GX);
  gru2_kernel<<<1, 768, 0, stream>>>(GX, WhhT, bhh, Wc, bc, out);
}

// Round 10
// 1269.321 us; speedup vs baseline: 1.9625x; 1.2540x over previous
//
#include <hip/hip_runtime.h>
#include <hip/hip_fp16.h>
#include <math.h>

#define T_ 12
#define N_ 20000
#define E_ 320000
#define FIN_ 128
#define H_ 256
#define G_ 256
#define C_ 10
#define ECH 8
#define EPC (E_ / ECH)
#define NB 32
#define BN_ (N_ / NB)   // 625 nodes per bucket
#define CAPB 11264      // LDS staging recs; overflow -> direct store

typedef __attribute__((ext_vector_type(8))) short bf16x8;
typedef __attribute__((ext_vector_type(4))) float f32x4;

// ---------------- workspace layout (bytes) ----------------
static const size_t OFF_EMB   = 0;          // T*256 f32 (zeroed each launch)
static const size_t ZERO_BYTES= 12288;
static const size_t OFF_DINV  = 12288;      // T*N f32
static const size_t OFF_CP    = 972288;     // T*(N+1) i32
static const size_t OFF_DEGP  = 1932544;    // T*ECH*N f32
static const size_t OFF_CNT16 = 9612544;    // T*ECH*N u16
static const size_t OFF_C16   = 13452544;   // T*E u16 packed cols
static const size_t OFF_RW    = 21132544;   // T*E u32 (row u16 | wt f16)
static const size_t OFF_EREC  = 36492544;   // T*E u32 CSR recs (row u16 | nm f16)
static const size_t OFF_W1BT  = 51852544;   // 256x128 bf16
static const size_t OFF_W2BT  = 51918080;   // 256x256 bf16
static const size_t OFF_WIHT  = 52049152;   // 256x768 f32
static const size_t OFF_WHHT  = 52835584;   // 256x768 f32
static const size_t OFF_GX    = 53622016;   // 12x768 f32
static const size_t OFF_RA    = 53658880;   // region A: NT*10.24MB (xbt then Q)
static const size_t PER_T_HALF= 5120000;    // N*128*2
static const size_t PER_T_FULL= 10240000;   // N*256*2
// region B (P128 then P2) at OFF_RA + NT*PER_T_FULL; total = OFF_RA + NT*20.48MB

__device__ __forceinline__ float bf2f(unsigned short u) {
  return __uint_as_float(((unsigned int)u) << 16);
}
__device__ __forceinline__ unsigned short f2bf(float f) {
  unsigned int u = __float_as_uint(f);
  unsigned int r = (u + 0x7FFFu + ((u >> 16) & 1u)) >> 16;  // RNE
  return (unsigned short)r;
}
__device__ __forceinline__ float bflo(unsigned int u) { return __uint_as_float(u << 16); }
__device__ __forceinline__ float bfhi(unsigned int u) { return __uint_as_float(u & 0xFFFF0000u); }
__device__ __forceinline__ unsigned int packbf(float lo, float hi) {
  return (unsigned int)f2bf(lo) | ((unsigned int)f2bf(hi) << 16);
}
__device__ __forceinline__ float rec2nm(unsigned int rec) {
  return __half2float(__ushort_as_half((unsigned short)(rec >> 16)));
}

// ---------------- partial histogram + stream packing ----------------
__global__ __launch_bounds__(1024) void histp(const int* __restrict__ ei,
                                              const float* __restrict__ ea,
                                              float* __restrict__ degp,
                                              unsigned short* __restrict__ cnt16,
                                              unsigned short* __restrict__ c16,
                                              unsigned int* __restrict__ rw) {
  __shared__ float degs[N_];            // 80 KB
  __shared__ unsigned int cntp[N_ / 2]; // 40 KB
  const int t = blockIdx.x, ech = blockIdx.y;
  const int tid = threadIdx.x;
  for (int i = tid; i < N_; i += 1024) degs[i] = 0.f;
  for (int i = tid; i < N_ / 2; i += 1024) cntp[i] = 0u;
  __syncthreads();
  const int eoff = ech * EPC;
  const int* rowp = ei + (size_t)t * 2 * E_ + eoff;
  const int* colp = rowp + E_;
  const float* wt = ea + (size_t)t * E_ + eoff;
  unsigned short* c16t = c16 + (size_t)t * E_ + eoff;
  unsigned int* rwt = rw + (size_t)t * E_ + eoff;
  for (int e = tid; e < EPC; e += 1024) {
    int c = colp[e];
    float wv = wt[e];
    atomicAdd(&degs[c], wv);
    atomicAdd(&cntp[c >> 1], 1u << ((c & 1) * 16));
    c16t[e] = (unsigned short)c;
    rwt[e] = (unsigned int)rowp[e] |
             ((unsigned int)__half_as_ushort(__float2half(wv)) << 16);
  }
  __syncthreads();
  float* dp = degp + ((size_t)t * ECH + ech) * N_;
  unsigned short* cp16 = cnt16 + ((size_t)t * ECH + ech) * N_;
  for (int i = tid; i < N_; i += 1024) {
    dp[i] = degs[i];
    cp16[i] = (unsigned short)((cntp[i >> 1] >> ((i & 1) * 16)) & 0xFFFFu);
  }
}

// ---------------- sum partials, scan -> colptr, dinv ----------------
__global__ __launch_bounds__(1024) void scanT(const unsigned short* __restrict__ cnt16,
                                              const float* __restrict__ degp,
                                              int* __restrict__ colptr,
                                              float* __restrict__ dinv) {
  const int t = blockIdx.x;
  __shared__ int s[1024];
  const int tid = threadIdx.x;
  int base = 0;
  for (int c0 = 0; c0 < N_; c0 += 1024) {
    int n = c0 + tid;
    int tot = 0;
    float dg = 0.f;
    if (n < N_) {
#pragma unroll
      for (int ch = 0; ch < ECH; ++ch) {
        tot += cnt16[((size_t)t * ECH + ch) * N_ + n];
        dg += degp[((size_t)t * ECH + ch) * N_ + n];
      }
    }
    s[tid] = tot;
    __syncthreads();
    for (int off = 1; off < 1024; off <<= 1) {
      int add = (tid >= off) ? s[tid - off] : 0;
      __syncthreads();
      s[tid] += add;
      __syncthreads();
    }
    if (n < N_) {
      colptr[t * (N_ + 1) + n] = base + s[tid] - tot;
      dinv[t * N_ + n] = rsqrtf(dg + 1.0f);
    }
    base += s[1023];
    __syncthreads();
  }
  if (tid == 0) colptr[t * (N_ + 1) + N_] = base;
}

// ---------------- bucketed CSR fill ----------------
__global__ __launch_bounds__(512) void fillB(const unsigned short* __restrict__ c16,
                                             const unsigned int* __restrict__ rw,
                                             const int* __restrict__ colptr,
                                             const float* __restrict__ dinv,
                                             unsigned int* __restrict__ erec) {
  __shared__ unsigned int data[CAPB];
  __shared__ unsigned int offp[BN_];
  __shared__ float dvb[BN_];
  const int t = blockIdx.x, b = blockIdx.y;
  const int tid = threadIdx.x;
  const int nlo = b * BN_;
  const int* cp = colptr + t * (N_ + 1);
  const int base = cp[nlo];
  const int bsize = cp[nlo + BN_] - base;
  const float* dv = dinv + (size_t)t * N_;
  for (int i = tid; i < BN_; i += 512) {
    offp[i] = (unsigned int)(cp[nlo + i] - base);
    dvb[i] = dv[nlo + i];
  }
  __syncthreads();
  const unsigned short* ct = c16 + (size_t)t * E_;
  const unsigned int* rwt = rw + (size_t)t * E_;
  unsigned int* eg = erec + (size_t)t * E_ + base;
  for (int e = tid; e < E_; e += 512) {
    unsigned int cl = (unsigned int)ct[e] - (unsigned int)nlo;
    if (cl < (unsigned int)BN_) {
      unsigned int r8 = rwt[e];
      int r = r8 & 0xFFFFu;
      float wv = __half2float(__ushort_as_half((unsigned short)(r8 >> 16)));
      float nm = dv[r] * wv * dvb[cl];
      unsigned int rec = (unsigned int)r |
                         ((unsigned int)__half_as_ushort(__float2half(nm)) << 16);
      unsigned int pos = atomicAdd(&offp[cl], 1u);
      if (pos < CAPB) data[pos] = rec;
      else eg[pos] = rec;
    }
  }
  __syncthreads();
  const int lim = bsize < CAPB ? bsize : CAPB;
  for (int i = tid; i < lim; i += 512) eg[i] = data[i];
}

// ---------------- weight prep ----------------
__global__ __launch_bounds__(256) void prep_kernel(const float* __restrict__ W1,
                                                   const float* __restrict__ W2,
                                                   const float* __restrict__ Wih,
                                                   const float* __restrict__ Whh,
                                                   unsigned short* __restrict__ W1bT,
                                                   unsigned short* __restrict__ W2bT,
                                                   float* __restrict__ WihT,
                                                   float* __restrict__ WhhT) {
  int idx = blockIdx.x * 256 + threadIdx.x;
  if (idx < 32768) {
    int n = idx >> 7, k = idx & 127;
    W1bT[idx] = f2bf(W1[k * 256 + n]);
  } else if (idx < 98304) {
    int j = idx - 32768;
    int n = j >> 8, k = j & 255;
    W2bT[j] = f2bf(W2[k * 256 + n]);
  } else if (idx < 294912) {
    int j = idx - 98304;
    int k = j / 768, c = j - k * 768;
    WihT[j] = Wih[c * 256 + k];
  } else if (idx < 491520) {
    int j = idx - 294912;
    int k = j / 768, c = j - k * 768;
    WhhT[j] = Whh[c * 256 + k];
  }
}

// ---------------- cast x_t fp32 -> bf16 (y = local t) ----------------
__global__ __launch_bounds__(256) void castx_kernel(const float* __restrict__ x,
                                                    unsigned short* __restrict__ xb,
                                                    int t_base) {
  const int tl = blockIdx.y;
  const int t = t_base + tl;
  const size_t q = (size_t)blockIdx.x * 256 + threadIdx.x;  // float4 units
  float4 v = ((const float4*)x)[(size_t)t * (N_ * FIN_ / 4) + q];
  ushort4 o;
  o.x = f2bf(v.x); o.y = f2bf(v.y); o.z = f2bf(v.z); o.w = f2bf(v.w);
  ((ushort4*)xb)[(size_t)tl * (N_ * FIN_ / 4) + q] = o;
}

// ---------------- gather aggregate: full-sector loads ----------------
__device__ __forceinline__ void agg_decode(int nt, int t_base, int& t, int& tl, int& node) {
  int bid = blockIdx.x;
  int L = bid;
  if (nt > 1) {
    int chunk = (int)(gridDim.x >> 3);
    L = (bid & 7) * chunk + (bid >> 3);
  }
  tl = L / 5000;
  node = (L - tl * 5000) * 4 + ((int)threadIdx.x >> 6);
  t = t_base + tl;
}

// 128-ch: quarter-wave (16 lanes x 16B) per edge, 4 edges in flight
__global__ __launch_bounds__(256) void agg128(const unsigned short* __restrict__ h,
                                              unsigned short* __restrict__ o,
                                              const unsigned int* __restrict__ erec,
                                              const int* __restrict__ colptr,
                                              const float* __restrict__ dinv,
                                              int t_base, int nt) {
  int t, tl, node;
  agg_decode(nt, t_base, t, tl, node);
  const int q = ((int)threadIdx.x >> 4) & 3;
  const int l16 = threadIdx.x & 15;
  const int me = threadIdx.x & 63;
  const unsigned int* ert = erec + (size_t)t * E_;
  const int* cp = colptr + t * (N_ + 1);
  const unsigned short* ht = h + (size_t)tl * N_ * 128;
  float a0 = 0.f, a1 = 0.f, a2 = 0.f, a3 = 0.f, a4 = 0.f, a5 = 0.f, a6 = 0.f, a7 = 0.f;
  const int s0 = cp[node], s1 = cp[node + 1];
  for (int i = s0 + q; i < s1; i += 4) {
    const unsigned int rec = ert[i];
    const int r = rec & 0xFFFFu;
    const float nm = rec2nm(rec);
    uint4 u = *(const uint4*)&ht[(size_t)r * 128 + l16 * 8];
    a0 = fmaf(nm, bflo(u.x), a0); a1 = fmaf(nm, bfhi(u.x), a1);
    a2 = fmaf(nm, bflo(u.y), a2); a3 = fmaf(nm, bfhi(u.y), a3);
    a4 = fmaf(nm, bflo(u.z), a4); a5 = fmaf(nm, bfhi(u.z), a5);
    a6 = fmaf(nm, bflo(u.w), a6); a7 = fmaf(nm, bfhi(u.w), a7);
  }
  if (q == 0) {
    const float di = dinv[(size_t)t * N_ + node];
    const float sw = di * di;
    uint4 us = *(const uint4*)&ht[(size_t)node * 128 + l16 * 8];
    a0 = fmaf(sw, bflo(us.x), a0); a1 = fmaf(sw, bfhi(us.x), a1);
    a2 = fmaf(sw, bflo(us.y), a2); a3 = fmaf(sw, bfhi(us.y), a3);
    a4 = fmaf(sw, bflo(us.z), a4); a5 = fmaf(sw, bfhi(us.z), a5);
    a6 = fmaf(sw, bflo(us.w), a6); a7 = fmaf(sw, bfhi(us.w), a7);
  }
  // combine quarters: q0 += q1 (and q2 += q3), then q0 += q2
  a0 += __shfl(a0, me | 16, 64); a1 += __shfl(a1, me | 16, 64);
  a2 += __shfl(a2, me | 16, 64); a3 += __shfl(a3, me | 16, 64);
  a4 += __shfl(a4, me | 16, 64); a5 += __shfl(a5, me | 16, 64);
  a6 += __shfl(a6, me | 16, 64); a7 += __shfl(a7, me | 16, 64);
  a0 += __shfl(a0, me | 32, 64); a1 += __shfl(a1, me | 32, 64);
  a2 += __shfl(a2, me | 32, 64); a3 += __shfl(a3, me | 32, 64);
  a4 += __shfl(a4, me | 32, 64); a5 += __shfl(a5, me | 32, 64);
  a6 += __shfl(a6, me | 32, 64); a7 += __shfl(a7, me | 32, 64);
  if (q == 0 && (me >> 4) == 0) {
    uint4 ov;
    ov.x = packbf(a0, a1); ov.y = packbf(a2, a3);
    ov.z = packbf(a4, a5); ov.w = packbf(a6, a7);
    *(uint4*)&o[((size_t)tl * N_ + node) * 128 + l16 * 8] = ov;
  }
}

// 256-ch: half-wave (32 lanes x 16B) per edge, 2 edges in flight
__global__ __launch_bounds__(256) void agg256(const unsigned short* __restrict__ h,
                                              unsigned short* __restrict__ o,
                                              const unsigned int* __restrict__ erec,
                                              const int* __restrict__ colptr,
                                              const float* __restrict__ dinv,
                                              int t_base, int nt) {
  int t, tl, node;
  agg_decode(nt, t_base, t, tl, node);
  const int hh = ((int)threadIdx.x >> 5) & 1;
  const int l32 = threadIdx.x & 31;
  const int me = threadIdx.x & 63;
  const unsigned int* ert = erec + (size_t)t * E_;
  const int* cp = colptr + t * (N_ + 1);
  const unsigned short* ht = h + (size_t)tl * N_ * 256;
  float a0 = 0.f, a1 = 0.f, a2 = 0.f, a3 = 0.f, a4 = 0.f, a5 = 0.f, a6 = 0.f, a7 = 0.f;
  const int s0 = cp[node], s1 = cp[node + 1];
  for (int i = s0 + hh; i < s1; i += 2) {
    const unsigned int rec = ert[i];
    const int r = rec & 0xFFFFu;
    const float nm = rec2nm(rec);
    uint4 u = *(const uint4*)&ht[(size_t)r * 256 + l32 * 8];
    a0 = fmaf(nm, bflo(u.x), a0); a1 = fmaf(nm, bfhi(u.x), a1);
    a2 = fmaf(nm, bflo(u.y), a2); a3 = fmaf(nm, bfhi(u.y), a3);
    a4 = fmaf(nm, bflo(u.z), a4); a5 = fmaf(nm, bfhi(u.z), a5);
    a6 = fmaf(nm, bflo(u.w), a6); a7 = fmaf(nm, bfhi(u.w), a7);
  }
  if (hh == 0) {
    const float di = dinv[(size_t)t * N_ + node];
    const float sw = di * di;
    uint4 us = *(const uint4*)&ht[(size_t)node * 256 + l32 * 8];
    a0 = fmaf(sw, bflo(us.x), a0); a1 = fmaf(sw, bfhi(us.x), a1);
    a2 = fmaf(sw, bflo(us.y), a2); a3 = fmaf(sw, bfhi(us.y), a3);
    a4 = fmaf(sw, bflo(us.z), a4); a5 = fmaf(sw, bfhi(us.z), a5);
    a6 = fmaf(sw, bflo(us.w), a6); a7 = fmaf(sw, bfhi(us.w), a7);
  }
  a0 += __shfl(a0, me | 32, 64); a1 += __shfl(a1, me | 32, 64);
  a2 += __shfl(a2, me | 32, 64); a3 += __shfl(a3, me | 32, 64);
  a4 += __shfl(a4, me | 32, 64); a5 += __shfl(a5, me | 32, 64);
  a6 += __shfl(a6, me | 32, 64); a7 += __shfl(a7, me | 32, 64);
  if (hh == 0) {
    uint4 ov;
    ov.x = packbf(a0, a1); ov.y = packbf(a2, a3);
    ov.z = packbf(a4, a5); ov.w = packbf(a6, a7);
    *(uint4*)&o[((size_t)tl * N_ + node) * 256 + l32 * 8] = ov;
  }
}

// ---------------- bf16 MFMA GEMM (z = local t); MEAN fuses column-mean ----------------
template <int K, bool MEAN>
__global__ __launch_bounds__(256) void gemm_bf16(const unsigned short* __restrict__ A,
                                                 const unsigned short* __restrict__ BT,
                                                 const float* __restrict__ bias,
                                                 unsigned short* __restrict__ C,
                                                 float* __restrict__ embp,
                                                 int t_base) {
  constexpr int LD = K + 8;
  __shared__ unsigned short As[64 * LD];
  __shared__ float cs[128];
  const int tid = threadIdx.x;
  const int tl = blockIdx.z;
  const int bm = blockIdx.x * 64;
  const int bn = blockIdx.y * 128;
  const unsigned short* At = A + (size_t)tl * N_ * K;
  if (MEAN && tid < 128) cs[tid] = 0.f;
  {
    constexpr int CPR = K / 8;
    constexpr int CH = 64 * CPR / 256;
#pragma unroll
    for (int i = 0; i < CH; ++i) {
      int chunk = tid + i * 256;
      int r = chunk / CPR;
      int ck = (chunk - r * CPR) * 8;
      int row = bm + r;
      if (row >= N_) row = N_ - 1;
      *(bf16x8*)&As[r * LD + ck] = *(const bf16x8*)&At[(size_t)row * K + ck];
    }
  }
  __syncthreads();
  const int w = tid >> 6, l = tid & 63;
  const int l16 = l & 15, lk = l >> 4;
  const int rbase = (w >> 1) * 32;
  const int colbase = bn + (w & 1) * 64;
  f32x4 acc[2][4] = {};
  for (int ks = 0; ks < K; ks += 32) {
    bf16x8 a[2], b[4];
#pragma unroll
    for (int m = 0; m < 2; ++m)
      a[m] = *(const bf16x8*)&As[(rbase + m * 16 + l16) * LD + ks + lk * 8];
#pragma unroll
    for (int n = 0; n < 4; ++n)
      b[n] = *(const bf16x8*)&BT[(size_t)(colbase + n * 16 + l16) * K + ks + lk * 8];
#pragma unroll
    for (int m = 0; m < 2; ++m)
#pragma unroll
      for (int n = 0; n < 4; ++n)
        acc[m][n] = __builtin_amdgcn_mfma_f32_16x16x32_bf16(a[m], b[n], acc[m][n], 0, 0, 0);
  }
#pragma unroll
  for (int n = 0; n < 4; ++n) {
    int col = colbase + n * 16 + l16;
    float bv = bias[col];
    float psum = 0.f;
#pragma unroll
    for (int m = 0; m < 2; ++m) {
      int row0 = bm + rbase + m * 16 + lk * 4;
#pragma unroll
      for (int r = 0; r < 4; ++r) {
        int row = row0 + r;
        if (row < N_) {
          float v = fmaxf(acc[m][n][r] + bv, 0.f);
          if (MEAN) psum += v;
          else C[((size_t)tl * N_ + row) * 256 + col] = f2bf(v);
        }
      }
    }
    if (MEAN) atomicAdd(&cs[col - bn], psum);
  }
  if (MEAN) {
    __syncthreads();
    if (tid < 128)
      atomicAdd(&embp[(t_base + tl) * 256 + bn + tid], cs[tid] * (1.0f / N_));
  }
}

// ---------------- GX[t] = Wih @ emb_t + bih ----------------
__global__ __launch_bounds__(768) void gx_kernel(const float* __restrict__ emb,
                                                 const float* __restrict__ WihT,
                                                 const float* __restrict__ bih,
                                                 float* __restrict__ GX) {
  const int t = blockIdx.x;
  const int tid = threadIdx.x;
  __shared__ float se[256];
  if (tid < 256) se[tid] = emb[t * 256 + tid];
  __syncthreads();
  float p0 = 0.f, p1 = 0.f, p2 = 0.f, p3 = 0.f;
#pragma unroll 8
  for (int k = 0; k < 256; k += 4) {
    p0 = fmaf(WihT[(size_t)(k + 0) * 768 + tid], se[k + 0], p0);
    p1 = fmaf(WihT[(size_t)(k + 1) * 768 + tid], se[k + 1], p1);
    p2 = fmaf(WihT[(size_t)(k + 2) * 768 + tid], se[k + 2], p2);
    p3 = fmaf(WihT[(size_t)(k + 3) * 768 + tid], se[k + 3], p3);
  }
  GX[t * 768 + tid] = (p0 + p1) + (p2 + p3) + bih[tid];
}

// ---------------- sequential GRU + final linear ----------------
__global__ __launch_bounds__(768) void gru2_kernel(const float* __restrict__ GX,
                                                   const float* __restrict__ WhhT,
                                                   const float* __restrict__ bhh,
                                                   const float* __restrict__ Wc,
                                                   const float* __restrict__ bc,
                                                   float* __restrict__ out) {
  __shared__ float sh[256];
  __shared__ float sgh[768];
  const int tid = threadIdx.x;
  if (tid < 256) sh[tid] = 0.f;
  __syncthreads();
  for (int t = 0; t < T_; ++t) {
    float p0 = 0.f, p1 = 0.f, p2 = 0.f, p3 = 0.f;
#pragma unroll 8
    for (int k = 0; k < 256; k += 4) {
      p0 = fmaf(WhhT[(size_t)(k + 0) * 768 + tid], sh[k + 0], p0);
      p1 = fmaf(WhhT[(size_t)(k + 1) * 768 + tid], sh[k + 1], p1);
      p2 = fmaf(WhhT[(size_t)(k + 2) * 768 + tid], sh[k + 2], p2);
      p3 = fmaf(WhhT[(size_t)(k + 3) * 768 + tid], sh[k + 3], p3);
    }
    sgh[tid] = (p0 + p1) + (p2 + p3) + bhh[tid];
    __syncthreads();
    if (tid < 256) {
      const float* gx = &GX[t * 768];
      float r = 1.f / (1.f + __expf(-(gx[tid] + sgh[tid])));
      float z = 1.f / (1.f + __expf(-(gx[256 + tid] + sgh[256 + tid])));
      float n = tanhf(gx[512 + tid] + r * sgh[512 + tid]);
      sh[tid] = (1.f - z) * n + z * sh[tid];
    }
    __syncthreads();
  }
  const int wv = tid >> 6, lane = tid & 63;
  if (wv < C_) {
    float p = 0.f;
#pragma unroll
    for (int i = 0; i < 4; ++i) {
      int j = lane + 64 * i;
      p += sh[j] * Wc[(size_t)j * C_ + wv];
    }
    for (int off = 32; off > 0; off >>= 1) p += __shfl_down(p, off);
    if (lane == 0) out[wv] = p + bc[wv];
  }
}

extern "C" void kernel_launch(void* const* d_in, const int* in_sizes, int n_in,
                              void* d_out, int out_size, void* d_ws, size_t ws_size,
                              hipStream_t stream) {
  const float* x   = (const float*)d_in[0];
  const int*   ei  = (const int*)d_in[1];
  const float* ea  = (const float*)d_in[2];
  const float* W1  = (const float*)d_in[3];
  const float* b1  = (const float*)d_in[4];
  const float* W2  = (const float*)d_in[5];
  const float* b2  = (const float*)d_in[6];
  const float* Wih = (const float*)d_in[7];
  const float* Whh = (const float*)d_in[8];
  const float* bih = (const float*)d_in[9];
  const float* bhh = (const float*)d_in[10];
  const float* Wc  = (const float*)d_in[11];
  const float* bc  = (const float*)d_in[12];
  float* out = (float*)d_out;

  char* w = (char*)d_ws;
  float* emb   = (float*)(w + OFF_EMB);
  float* dinv  = (float*)(w + OFF_DINV);
  int*   cp    = (int*)(w + OFF_CP);
  float* degp  = (float*)(w + OFF_DEGP);
  unsigned short* cnt16 = (unsigned short*)(w + OFF_CNT16);
  unsigned short* c16   = (unsigned short*)(w + OFF_C16);
  unsigned int* rw   = (unsigned int*)(w + OFF_RW);
  unsigned int* erec = (unsigned int*)(w + OFF_EREC);
  unsigned short* W1bT = (unsigned short*)(w + OFF_W1BT);
  unsigned short* W2bT = (unsigned short*)(w + OFF_W2BT);
  float* WihT  = (float*)(w + OFF_WIHT);
  float* WhhT  = (float*)(w + OFF_WHHT);
  float* GX    = (float*)(w + OFF_GX);

  // adaptive group size: region A + region B = NT * 20.48 MB beyond OFF_RA
  int NT = 1;
  if (ws_size > OFF_RA + 2 * PER_T_FULL) {
    size_t avail = ws_size - OFF_RA;
    size_t nt = avail / (2 * PER_T_FULL);
    NT = (int)(nt < 12 ? nt : 12);
    if (NT < 1) NT = 1;
  }
  unsigned short* regA = (unsigned short*)(w + OFF_RA);
  unsigned short* regB = (unsigned short*)(w + OFF_RA + (size_t)NT * PER_T_FULL);
  unsigned short* xbt  = regA;  // NT*N*128
  unsigned short* Q    = regA;  // NT*N*256 (xbt dead by then)
  unsigned short* P128 = regB;  // NT*N*128
  unsigned short* P2   = regB;  // NT*N*256 (P128 dead by then)

  hipMemsetAsync(d_ws, 0, ZERO_BYTES, stream);

  prep_kernel<<<1920, 256, 0, stream>>>(W1, W2, Wih, Whh, W1bT, W2bT, WihT, WhhT);

  dim3 hist_grid(T_, ECH);
  histp<<<hist_grid, 1024, 0, stream>>>(ei, ea, degp, cnt16, c16, rw);
  scanT<<<T_, 1024, 0, stream>>>(cnt16, degp, cp, dinv);
  dim3 fill_grid(T_, NB);
  fillB<<<fill_grid, 512, 0, stream>>>(c16, rw, cp, dinv, erec);

  for (int t0 = 0; t0 < T_; t0 += NT) {
    const int nt = (T_ - t0) < NT ? (T_ - t0) : NT;
    castx_kernel<<<dim3(2500, nt), 256, 0, stream>>>(x, xbt, t0);
    agg128<<<nt * 5000, 256, 0, stream>>>(xbt, P128, erec, cp, dinv, t0, nt);
    gemm_bf16<FIN_, false><<<dim3(313, 2, nt), 256, 0, stream>>>(P128, W1bT, b1, Q, nullptr, t0);
    agg256<<<nt * 5000, 256, 0, stream>>>(Q, P2, erec, cp, dinv, t0, nt);
    gemm_bf16<H_, true><<<dim3(313, 2, nt), 256, 0, stream>>>(P2, W2bT, b2, nullptr, emb, t0);
  }
  gx_kernel<<<T_, 768, 0, stream>>>(emb, WihT, bih, GX);
  gru2_kernel<<<1, 768, 0, stream>>>(GX, WhhT, bhh, Wc, bc, out);
}

// Round 11
// 1071.574 us; speedup vs baseline: 2.3246x; 1.1845x over previous
//
#include <hip/hip_runtime.h>
#include <hip/hip_fp16.h>
#include <math.h>

#define T_ 12
#define N_ 20000
#define E_ 320000
#define FIN_ 128
#define H_ 256
#define G_ 256
#define C_ 10
#define ECH 8
#define EPC (E_ / ECH)   // 40000 edges per chunk
#define NB 20            // node buckets of 1024 (bucket = node >> 10)
#define BNODES 1024
#define CAPF 18432       // fillB2 LDS staging recs (mean 16384 + 16 sigma); overflow -> direct

typedef __attribute__((ext_vector_type(8))) short bf16x8;
typedef __attribute__((ext_vector_type(4))) float f32x4;

// ---------------- workspace layout (bytes) ----------------
static const size_t OFF_EMB   = 0;          // T*256 f32 (zeroed each launch)
static const size_t ZERO_BYTES= 12288;
static const size_t OFF_DINV  = 12288;      // T*N f32                     -> 972288
static const size_t OFF_CP    = 972288;     // T*(N+1) i32 (pad 960256)    -> 1932544
static const size_t OFF_DEGP  = 1932544;    // T*ECH*N f32 [dead after scanT]
static const size_t OFF_CNT16 = 9612544;    // T*ECH*N u16 [dead after pcount]
static const size_t OFF_EBIN  = 1932544;    // T*E uint2 (ALIASES degp+cnt16) -> 32652544
static const size_t OFF_PCNT  = 32652544;   // T*ECH*NB u32                -> 32660224
static const size_t OFF_POFF  = 32660224;   // T*168 u32                   -> 32668288
static const size_t OFF_EREC  = 32668288;   // T*E u32 CSR (row u16|nm f16)-> 48028288
static const size_t OFF_W1BT  = 48028288;   // 256x128 bf16
static const size_t OFF_W2BT  = 48093824;   // 256x256 bf16
static const size_t OFF_WIHT  = 48224896;   // 256x768 f32
static const size_t OFF_WHHT  = 49011328;   // 256x768 f32
static const size_t OFF_GX    = 49797760;   // 12x768 f32
static const size_t OFF_RA    = 49834624;   // region A: NT*10.24MB (xbt then Q)
static const size_t PER_T_FULL= 10240000;   // N*256*2
// region B (P128 then P2) at OFF_RA + NT*PER_T_FULL; min footprint = OFF_RA + 2*PER_T_FULL ~ 70.3MB

__device__ __forceinline__ float bf2f(unsigned short u) {
  return __uint_as_float(((unsigned int)u) << 16);
}
__device__ __forceinline__ unsigned short f2bf(float f) {
  unsigned int u = __float_as_uint(f);
  unsigned int r = (u + 0x7FFFu + ((u >> 16) & 1u)) >> 16;  // RNE
  return (unsigned short)r;
}
__device__ __forceinline__ float bflo(unsigned int u) { return __uint_as_float(u << 16); }
__device__ __forceinline__ float bfhi(unsigned int u) { return __uint_as_float(u & 0xFFFF0000u); }
__device__ __forceinline__ unsigned int packbf(float lo, float hi) {
  return (unsigned int)f2bf(lo) | ((unsigned int)f2bf(hi) << 16);
}
__device__ __forceinline__ float rec2nm(unsigned int rec) {
  return __half2float(__ushort_as_half((unsigned short)(rec >> 16)));
}

// ---------------- partial histogram: block (t, ech) owns edges [ech*EPC, +EPC) ----------------
__global__ __launch_bounds__(1024) void histp(const int* __restrict__ ei,
                                              const float* __restrict__ ea,
                                              float* __restrict__ degp,
                                              unsigned short* __restrict__ cnt16) {
  __shared__ float degs[N_];            // 80 KB
  __shared__ unsigned int cntp[N_ / 2]; // 40 KB
  const int t = blockIdx.x, ech = blockIdx.y;
  const int tid = threadIdx.x;
  for (int i = tid; i < N_; i += 1024) degs[i] = 0.f;
  for (int i = tid; i < N_ / 2; i += 1024) cntp[i] = 0u;
  __syncthreads();
  const int* col = ei + (size_t)t * 2 * E_ + E_ + ech * EPC;
  const float* wt = ea + (size_t)t * E_ + ech * EPC;
  for (int e = tid; e < EPC; e += 1024) {
    int c = col[e];
    atomicAdd(&degs[c], wt[e]);
    atomicAdd(&cntp[c >> 1], 1u << ((c & 1) * 16));
  }
  __syncthreads();
  float* dp = degp + ((size_t)t * ECH + ech) * N_;
  unsigned short* cp16 = cnt16 + ((size_t)t * ECH + ech) * N_;
  for (int i = tid; i < N_; i += 1024) {
    dp[i] = degs[i];
    cp16[i] = (unsigned short)((cntp[i >> 1] >> ((i & 1) * 16)) & 0xFFFFu);
  }
}

// ---------------- sum partials, scan -> colptr, dinv ----------------
__global__ __launch_bounds__(1024) void scanT(const unsigned short* __restrict__ cnt16,
                                              const float* __restrict__ degp,
                                              int* __restrict__ colptr,
                                              float* __restrict__ dinv) {
  const int t = blockIdx.x;
  __shared__ int s[1024];
  const int tid = threadIdx.x;
  int base = 0;
  for (int c0 = 0; c0 < N_; c0 += 1024) {
    int n = c0 + tid;
    int tot = 0;
    float dg = 0.f;
    if (n < N_) {
#pragma unroll
      for (int ch = 0; ch < ECH; ++ch) {
        tot += cnt16[((size_t)t * ECH + ch) * N_ + n];
        dg += degp[((size_t)t * ECH + ch) * N_ + n];
      }
    }
    s[tid] = tot;
    __syncthreads();
    for (int off = 1; off < 1024; off <<= 1) {
      int add = (tid >= off) ? s[tid - off] : 0;
      __syncthreads();
      s[tid] += add;
      __syncthreads();
    }
    if (n < N_) {
      colptr[t * (N_ + 1) + n] = base + s[tid] - tot;
      dinv[t * N_ + n] = rsqrtf(dg + 1.0f);
    }
    base += s[1023];
    __syncthreads();
  }
  if (tid == 0) colptr[t * (N_ + 1) + N_] = base;
}

// ---------------- bucket counts per (t, ech): from cnt16, no edge re-read ----------------
__global__ __launch_bounds__(256) void pcount(const unsigned short* __restrict__ cnt16,
                                              unsigned int* __restrict__ pcnt) {
  __shared__ unsigned int psum[NB];
  const int t = blockIdx.x, ech = blockIdx.y;
  const int tid = threadIdx.x;
  if (tid < NB) psum[tid] = 0u;
  __syncthreads();
  const unsigned short* cc = cnt16 + ((size_t)t * ECH + ech) * N_;
  for (int c0 = 0; c0 < N_; c0 += 256) {
    int n = c0 + tid;
    unsigned int v = (n < N_) ? (unsigned int)cc[n] : 0u;
#pragma unroll
    for (int off = 32; off; off >>= 1) v += __shfl_down(v, off, 64);
    if ((tid & 63) == 0) atomicAdd(&psum[c0 >> 10], v);  // chunk of 256 spans one bucket
  }
  __syncthreads();
  if (tid < NB) pcnt[((size_t)t * ECH + ech) * NB + tid] = psum[tid];
}

// ---------------- per-(bucket, chunk) stream offsets, bucket-major ----------------
__global__ void partS(const unsigned int* __restrict__ pcnt,
                      unsigned int* __restrict__ poff) {
  const int t = threadIdx.x;
  if (t >= T_) return;
  unsigned int run = 0;
  for (int b = 0; b < NB; ++b)
    for (int ech = 0; ech < ECH; ++ech) {
      poff[t * 168 + b * 8 + ech] = run;
      run += pcnt[((size_t)t * ECH + ech) * NB + b];
    }
  poff[t * 168 + 160] = run;  // == E
}

// ---------------- partition scatter: each edge touched once, 20 streams/block ----------------
__global__ __launch_bounds__(512) void partW(const int* __restrict__ ei,
                                             const float* __restrict__ ea,
                                             const float* __restrict__ dinv,
                                             const unsigned int* __restrict__ poff,
                                             uint2* __restrict__ ebin) {
  __shared__ unsigned int cursor[NB];
  const int t = blockIdx.x, ech = blockIdx.y;
  const int tid = threadIdx.x;
  if (tid < NB) cursor[tid] = poff[t * 168 + tid * 8 + ech];
  __syncthreads();
  const int eoff = ech * EPC;
  const int* rowp = ei + (size_t)t * 2 * E_ + eoff;
  const int* colp = rowp + E_;
  const float* wt = ea + (size_t)t * E_ + eoff;
  const float* dv = dinv + (size_t)t * N_;
  uint2* eb = ebin + (size_t)t * E_;
  for (int e = tid; e < EPC; e += 512) {
    int c = colp[e], r = rowp[e];
    float nm = dv[r] * wt[e] * dv[c];
    unsigned int pos = atomicAdd(&cursor[c >> 10], 1u);
    uint2 rec;
    rec.x = (unsigned int)(c & 1023) | ((unsigned int)r << 16);
    rec.y = (unsigned int)__half_as_ushort(__float2half(nm));
    eb[pos] = rec;
  }
}

// ---------------- CSR fill: block (t,b) reads ONLY its bucket's recs, LDS scatter ----------------
__global__ __launch_bounds__(512) void fillB2(const uint2* __restrict__ ebin,
                                              const int* __restrict__ colptr,
                                              unsigned int* __restrict__ erec) {
  __shared__ unsigned int data[CAPF];   // 72 KB
  __shared__ unsigned int offp[BNODES]; // 4 KB
  const int t = blockIdx.x, b = blockIdx.y;
  const int tid = threadIdx.x;
  const int nlo = b << 10;
  const int nnodes = (N_ - nlo < BNODES) ? (N_ - nlo) : BNODES;
  const int* cp = colptr + t * (N_ + 1);
  const int base = cp[nlo];
  const int bsize = cp[nlo + nnodes] - base;
  for (int i = tid; i < nnodes; i += 512) offp[i] = (unsigned int)(cp[nlo + i] - base);
  __syncthreads();
  const uint2* eb = ebin + (size_t)t * E_ + base;
  unsigned int* eg = erec + (size_t)t * E_ + base;
  for (int i = tid; i < bsize; i += 512) {
    uint2 rec = eb[i];
    unsigned int cl = rec.x & 0xFFFFu;
    unsigned int rec4 = (rec.x >> 16) | (rec.y << 16);  // row | nm<<16
    unsigned int pos = atomicAdd(&offp[cl], 1u);
    if (pos < CAPF) data[pos] = rec4;
    else eg[pos] = rec4;
  }
  __syncthreads();
  const int lim = bsize < CAPF ? bsize : CAPF;
  for (int i = tid; i < lim; i += 512) eg[i] = data[i];
}

// ---------------- weight prep ----------------
__global__ __launch_bounds__(256) void prep_kernel(const float* __restrict__ W1,
                                                   const float* __restrict__ W2,
                                                   const float* __restrict__ Wih,
                                                   const float* __restrict__ Whh,
                                                   unsigned short* __restrict__ W1bT,
                                                   unsigned short* __restrict__ W2bT,
                                                   float* __restrict__ WihT,
                                                   float* __restrict__ WhhT) {
  int idx = blockIdx.x * 256 + threadIdx.x;
  if (idx < 32768) {
    int n = idx >> 7, k = idx & 127;
    W1bT[idx] = f2bf(W1[k * 256 + n]);
  } else if (idx < 98304) {
    int j = idx - 32768;
    int n = j >> 8, k = j & 255;
    W2bT[j] = f2bf(W2[k * 256 + n]);
  } else if (idx < 294912) {
    int j = idx - 98304;
    int k = j / 768, c = j - k * 768;
    WihT[j] = Wih[c * 256 + k];
  } else if (idx < 491520) {
    int j = idx - 294912;
    int k = j / 768, c = j - k * 768;
    WhhT[j] = Whh[c * 256 + k];
  }
}

// ---------------- cast x_t fp32 -> bf16 (y = local t) ----------------
__global__ __launch_bounds__(256) void castx_kernel(const float* __restrict__ x,
                                                    unsigned short* __restrict__ xb,
                                                    int t_base) {
  const int tl = blockIdx.y;
  const int t = t_base + tl;
  const size_t q = (size_t)blockIdx.x * 256 + threadIdx.x;  // float4 units
  float4 v = ((const float4*)x)[(size_t)t * (N_ * FIN_ / 4) + q];
  ushort4 o;
  o.x = f2bf(v.x); o.y = f2bf(v.y); o.z = f2bf(v.z); o.w = f2bf(v.w);
  ((ushort4*)xb)[(size_t)tl * (N_ * FIN_ / 4) + q] = o;
}

// ---------------- gather aggregate: full-sector loads ----------------
__device__ __forceinline__ void agg_decode(int nt, int t_base, int& t, int& tl, int& node) {
  int bid = blockIdx.x;
  int L = bid;
  if (nt > 1) {
    int chunk = (int)(gridDim.x >> 3);
    L = (bid & 7) * chunk + (bid >> 3);
  }
  tl = L / 5000;
  node = (L - tl * 5000) * 4 + ((int)threadIdx.x >> 6);
  t = t_base + tl;
}

// 128-ch: quarter-wave (16 lanes x 16B) per edge, 4 edges in flight
__global__ __launch_bounds__(256) void agg128(const unsigned short* __restrict__ h,
                                              unsigned short* __restrict__ o,
                                              const unsigned int* __restrict__ erec,
                                              const int* __restrict__ colptr,
                                              const float* __restrict__ dinv,
                                              int t_base, int nt) {
  int t, tl, node;
  agg_decode(nt, t_base, t, tl, node);
  const int q = ((int)threadIdx.x >> 4) & 3;
  const int l16 = threadIdx.x & 15;
  const int me = threadIdx.x & 63;
  const unsigned int* ert = erec + (size_t)t * E_;
  const int* cp = colptr + t * (N_ + 1);
  const unsigned short* ht = h + (size_t)tl * N_ * 128;
  float a0 = 0.f, a1 = 0.f, a2 = 0.f, a3 = 0.f, a4 = 0.f, a5 = 0.f, a6 = 0.f, a7 = 0.f;
  const int s0 = cp[node], s1 = cp[node + 1];
  for (int i = s0 + q; i < s1; i += 4) {
    const unsigned int rec = ert[i];
    const int r = rec & 0xFFFFu;
    const float nm = rec2nm(rec);
    uint4 u = *(const uint4*)&ht[(size_t)r * 128 + l16 * 8];
    a0 = fmaf(nm, bflo(u.x), a0); a1 = fmaf(nm, bfhi(u.x), a1);
    a2 = fmaf(nm, bflo(u.y), a2); a3 = fmaf(nm, bfhi(u.y), a3);
    a4 = fmaf(nm, bflo(u.z), a4); a5 = fmaf(nm, bfhi(u.z), a5);
    a6 = fmaf(nm, bflo(u.w), a6); a7 = fmaf(nm, bfhi(u.w), a7);
  }
  if (q == 0) {
    const float di = dinv[(size_t)t * N_ + node];
    const float sw = di * di;
    uint4 us = *(const uint4*)&ht[(size_t)node * 128 + l16 * 8];
    a0 = fmaf(sw, bflo(us.x), a0); a1 = fmaf(sw, bfhi(us.x), a1);
    a2 = fmaf(sw, bflo(us.y), a2); a3 = fmaf(sw, bfhi(us.y), a3);
    a4 = fmaf(sw, bflo(us.z), a4); a5 = fmaf(sw, bfhi(us.z), a5);
    a6 = fmaf(sw, bflo(us.w), a6); a7 = fmaf(sw, bfhi(us.w), a7);
  }
  a0 += __shfl(a0, me | 16, 64); a1 += __shfl(a1, me | 16, 64);
  a2 += __shfl(a2, me | 16, 64); a3 += __shfl(a3, me | 16, 64);
  a4 += __shfl(a4, me | 16, 64); a5 += __shfl(a5, me | 16, 64);
  a6 += __shfl(a6, me | 16, 64); a7 += __shfl(a7, me | 16, 64);
  a0 += __shfl(a0, me | 32, 64); a1 += __shfl(a1, me | 32, 64);
  a2 += __shfl(a2, me | 32, 64); a3 += __shfl(a3, me | 32, 64);
  a4 += __shfl(a4, me | 32, 64); a5 += __shfl(a5, me | 32, 64);
  a6 += __shfl(a6, me | 32, 64); a7 += __shfl(a7, me | 32, 64);
  if (q == 0 && (me >> 4) == 0) {
    uint4 ov;
    ov.x = packbf(a0, a1); ov.y = packbf(a2, a3);
    ov.z = packbf(a4, a5); ov.w = packbf(a6, a7);
    *(uint4*)&o[((size_t)tl * N_ + node) * 128 + l16 * 8] = ov;
  }
}

// 256-ch: half-wave (32 lanes x 16B) per edge, 2 edges in flight
__global__ __launch_bounds__(256) void agg256(const unsigned short* __restrict__ h,
                                              unsigned short* __restrict__ o,
                                              const unsigned int* __restrict__ erec,
                                              const int* __restrict__ colptr,
                                              const float* __restrict__ dinv,
                                              int t_base, int nt) {
  int t, tl, node;
  agg_decode(nt, t_base, t, tl, node);
  const int hh = ((int)threadIdx.x >> 5) & 1;
  const int l32 = threadIdx.x & 31;
  const int me = threadIdx.x & 63;
  const unsigned int* ert = erec + (size_t)t * E_;
  const int* cp = colptr + t * (N_ + 1);
  const unsigned short* ht = h + (size_t)tl * N_ * 256;
  float a0 = 0.f, a1 = 0.f, a2 = 0.f, a3 = 0.f, a4 = 0.f, a5 = 0.f, a6 = 0.f, a7 = 0.f;
  const int s0 = cp[node], s1 = cp[node + 1];
  for (int i = s0 + hh; i < s1; i += 2) {
    const unsigned int rec = ert[i];
    const int r = rec & 0xFFFFu;
    const float nm = rec2nm(rec);
    uint4 u = *(const uint4*)&ht[(size_t)r * 256 + l32 * 8];
    a0 = fmaf(nm, bflo(u.x), a0); a1 = fmaf(nm, bfhi(u.x), a1);
    a2 = fmaf(nm, bflo(u.y), a2); a3 = fmaf(nm, bfhi(u.y), a3);
    a4 = fmaf(nm, bflo(u.z), a4); a5 = fmaf(nm, bfhi(u.z), a5);
    a6 = fmaf(nm, bflo(u.w), a6); a7 = fmaf(nm, bfhi(u.w), a7);
  }
  if (hh == 0) {
    const float di = dinv[(size_t)t * N_ + node];
    const float sw = di * di;
    uint4 us = *(const uint4*)&ht[(size_t)node * 256 + l32 * 8];
    a0 = fmaf(sw, bflo(us.x), a0); a1 = fmaf(sw, bfhi(us.x), a1);
    a2 = fmaf(sw, bflo(us.y), a2); a3 = fmaf(sw, bfhi(us.y), a3);
    a4 = fmaf(sw, bflo(us.z), a4); a5 = fmaf(sw, bfhi(us.z), a5);
    a6 = fmaf(sw, bflo(us.w), a6); a7 = fmaf(sw, bfhi(us.w), a7);
  }
  a0 += __shfl(a0, me | 32, 64); a1 += __shfl(a1, me | 32, 64);
  a2 += __shfl(a2, me | 32, 64); a3 += __shfl(a3, me | 32, 64);
  a4 += __shfl(a4, me | 32, 64); a5 += __shfl(a5, me | 32, 64);
  a6 += __shfl(a6, me | 32, 64); a7 += __shfl(a7, me | 32, 64);
  if (hh == 0) {
    uint4 ov;
    ov.x = packbf(a0, a1); ov.y = packbf(a2, a3);
    ov.z = packbf(a4, a5); ov.w = packbf(a6, a7);
    *(uint4*)&o[((size_t)tl * N_ + node) * 256 + l32 * 8] = ov;
  }
}

// ---------------- bf16 MFMA GEMM (z = local t); MEAN fuses column-mean ----------------
template <int K, bool MEAN>
__global__ __launch_bounds__(256) void gemm_bf16(const unsigned short* __restrict__ A,
                                                 const unsigned short* __restrict__ BT,
                                                 const float* __restrict__ bias,
                                                 unsigned short* __restrict__ C,
                                                 float* __restrict__ embp,
                                                 int t_base) {
  constexpr int LD = K + 8;
  __shared__ unsigned short As[64 * LD];
  __shared__ float cs[128];
  const int tid = threadIdx.x;
  const int tl = blockIdx.z;
  const int bm = blockIdx.x * 64;
  const int bn = blockIdx.y * 128;
  const unsigned short* At = A + (size_t)tl * N_ * K;
  if (MEAN && tid < 128) cs[tid] = 0.f;
  {
    constexpr int CPR = K / 8;
    constexpr int CH = 64 * CPR / 256;
#pragma unroll
    for (int i = 0; i < CH; ++i) {
      int chunk = tid + i * 256;
      int r = chunk / CPR;
      int ck = (chunk - r * CPR) * 8;
      int row = bm + r;
      if (row >= N_) row = N_ - 1;
      *(bf16x8*)&As[r * LD + ck] = *(const bf16x8*)&At[(size_t)row * K + ck];
    }
  }
  __syncthreads();
  const int w = tid >> 6, l = tid & 63;
  const int l16 = l & 15, lk = l >> 4;
  const int rbase = (w >> 1) * 32;
  const int colbase = bn + (w & 1) * 64;
  f32x4 acc[2][4] = {};
  for (int ks = 0; ks < K; ks += 32) {
    bf16x8 a[2], b[4];
#pragma unroll
    for (int m = 0; m < 2; ++m)
      a[m] = *(const bf16x8*)&As[(rbase + m * 16 + l16) * LD + ks + lk * 8];
#pragma unroll
    for (int n = 0; n < 4; ++n)
      b[n] = *(const bf16x8*)&BT[(size_t)(colbase + n * 16 + l16) * K + ks + lk * 8];
#pragma unroll
    for (int m = 0; m < 2; ++m)
#pragma unroll
      for (int n = 0; n < 4; ++n)
        acc[m][n] = __builtin_amdgcn_mfma_f32_16x16x32_bf16(a[m], b[n], acc[m][n], 0, 0, 0);
  }
#pragma unroll
  for (int n = 0; n < 4; ++n) {
    int col = colbase + n * 16 + l16;
    float bv = bias[col];
    float psum = 0.f;
#pragma unroll
    for (int m = 0; m < 2; ++m) {
      int row0 = bm + rbase + m * 16 + lk * 4;
#pragma unroll
      for (int r = 0; r < 4; ++r) {
        int row = row0 + r;
        if (row < N_) {
          float v = fmaxf(acc[m][n][r] + bv, 0.f);
          if (MEAN) psum += v;
          else C[((size_t)tl * N_ + row) * 256 + col] = f2bf(v);
        }
      }
    }
    if (MEAN) atomicAdd(&cs[col - bn], psum);
  }
  if (MEAN) {
    __syncthreads();
    if (tid < 128)
      atomicAdd(&embp[(t_base + tl) * 256 + bn + tid], cs[tid] * (1.0f / N_));
  }
}

// ---------------- GX[t] = Wih @ emb_t + bih ----------------
__global__ __launch_bounds__(768) void gx_kernel(const float* __restrict__ emb,
                                                 const float* __restrict__ WihT,
                                                 const float* __restrict__ bih,
                                                 float* __restrict__ GX) {
  const int t = blockIdx.x;
  const int tid = threadIdx.x;
  __shared__ float se[256];
  if (tid < 256) se[tid] = emb[t * 256 + tid];
  __syncthreads();
  float p0 = 0.f, p1 = 0.f, p2 = 0.f, p3 = 0.f;
#pragma unroll 8
  for (int k = 0; k < 256; k += 4) {
    p0 = fmaf(WihT[(size_t)(k + 0) * 768 + tid], se[k + 0], p0);
    p1 = fmaf(WihT[(size_t)(k + 1) * 768 + tid], se[k + 1], p1);
    p2 = fmaf(WihT[(size_t)(k + 2) * 768 + tid], se[k + 2], p2);
    p3 = fmaf(WihT[(size_t)(k + 3) * 768 + tid], se[k + 3], p3);
  }
  GX[t * 768 + tid] = (p0 + p1) + (p2 + p3) + bih[tid];
}

// ---------------- sequential GRU + final linear ----------------
__global__ __launch_bounds__(768) void gru2_kernel(const float* __restrict__ GX,
                                                   const float* __restrict__ WhhT,
                                                   const float* __restrict__ bhh,
                                                   const float* __restrict__ Wc,
                                                   const float* __restrict__ bc,
                                                   float* __restrict__ out) {
  __shared__ float sh[256];
  __shared__ float sgh[768];
  const int tid = threadIdx.x;
  if (tid < 256) sh[tid] = 0.f;
  __syncthreads();
  for (int t = 0; t < T_; ++t) {
    float p0 = 0.f, p1 = 0.f, p2 = 0.f, p3 = 0.f;
#pragma unroll 8
    for (int k = 0; k < 256; k += 4) {
      p0 = fmaf(WhhT[(size_t)(k + 0) * 768 + tid], sh[k + 0], p0);
      p1 = fmaf(WhhT[(size_t)(k + 1) * 768 + tid], sh[k + 1], p1);
      p2 = fmaf(WhhT[(size_t)(k + 2) * 768 + tid], sh[k + 2], p2);
      p3 = fmaf(WhhT[(size_t)(k + 3) * 768 + tid], sh[k + 3], p3);
    }
    sgh[tid] = (p0 + p1) + (p2 + p3) + bhh[tid];
    __syncthreads();
    if (tid < 256) {
      const float* gx = &GX[t * 768];
      float r = 1.f / (1.f + __expf(-(gx[tid] + sgh[tid])));
      float z = 1.f / (1.f + __expf(-(gx[256 + tid] + sgh[256 + tid])));
      float n = tanhf(gx[512 + tid] + r * sgh[512 + tid]);
      sh[tid] = (1.f - z) * n + z * sh[tid];
    }
    __syncthreads();
  }
  const int wv = tid >> 6, lane = tid & 63;
  if (wv < C_) {
    float p = 0.f;
#pragma unroll
    for (int i = 0; i < 4; ++i) {
      int j = lane + 64 * i;
      p += sh[j] * Wc[(size_t)j * C_ + wv];
    }
    for (int off = 32; off > 0; off >>= 1) p += __shfl_down(p, off);
    if (lane == 0) out[wv] = p + bc[wv];
  }
}

extern "C" void kernel_launch(void* const* d_in, const int* in_sizes, int n_in,
                              void* d_out, int out_size, void* d_ws, size_t ws_size,
                              hipStream_t stream) {
  const float* x   = (const float*)d_in[0];
  const int*   ei  = (const int*)d_in[1];
  const float* ea  = (const float*)d_in[2];
  const float* W1  = (const float*)d_in[3];
  const float* b1  = (const float*)d_in[4];
  const float* W2  = (const float*)d_in[5];
  const float* b2  = (const float*)d_in[6];
  const float* Wih = (const float*)d_in[7];
  const float* Whh = (const float*)d_in[8];
  const float* bih = (const float*)d_in[9];
  const float* bhh = (const float*)d_in[10];
  const float* Wc  = (const float*)d_in[11];
  const float* bc  = (const float*)d_in[12];
  float* out = (float*)d_out;

  char* w = (char*)d_ws;
  float* emb   = (float*)(w + OFF_EMB);
  float* dinv  = (float*)(w + OFF_DINV);
  int*   cp    = (int*)(w + OFF_CP);
  float* degp  = (float*)(w + OFF_DEGP);
  unsigned short* cnt16 = (unsigned short*)(w + OFF_CNT16);
  uint2* ebin  = (uint2*)(w + OFF_EBIN);
  unsigned int* pcnt = (unsigned int*)(w + OFF_PCNT);
  unsigned int* poff = (unsigned int*)(w + OFF_POFF);
  unsigned int* erec = (unsigned int*)(w + OFF_EREC);
  unsigned short* W1bT = (unsigned short*)(w + OFF_W1BT);
  unsigned short* W2bT = (unsigned short*)(w + OFF_W2BT);
  float* WihT  = (float*)(w + OFF_WIHT);
  float* WhhT  = (float*)(w + OFF_WHHT);
  float* GX    = (float*)(w + OFF_GX);

  // adaptive group size: region A + region B = NT * 20.48 MB beyond OFF_RA
  int NT = 1;
  if (ws_size > OFF_RA + 2 * PER_T_FULL) {
    size_t avail = ws_size - OFF_RA;
    size_t nt = avail / (2 * PER_T_FULL);
    NT = (int)(nt < 12 ? nt : 12);
    if (NT < 1) NT = 1;
  }
  unsigned short* regA = (unsigned short*)(w + OFF_RA);
  unsigned short* regB = (unsigned short*)(w + OFF_RA + (size_t)NT * PER_T_FULL);
  unsigned short* xbt  = regA;  // NT*N*128
  unsigned short* Q    = regA;  // NT*N*256 (xbt dead by then)
  unsigned short* P128 = regB;  // NT*N*128
  unsigned short* P2   = regB;  // NT*N*256 (P128 dead by then)

  hipMemsetAsync(d_ws, 0, ZERO_BYTES, stream);

  prep_kernel<<<1920, 256, 0, stream>>>(W1, W2, Wih, Whh, W1bT, W2bT, WihT, WhhT);

  dim3 te_grid(T_, ECH);
  histp<<<te_grid, 1024, 0, stream>>>(ei, ea, degp, cnt16);
  scanT<<<T_, 1024, 0, stream>>>(cnt16, degp, cp, dinv);
  pcount<<<te_grid, 256, 0, stream>>>(cnt16, pcnt);
  partS<<<1, 64, 0, stream>>>(pcnt, poff);
  partW<<<te_grid, 512, 0, stream>>>(ei, ea, dinv, poff, ebin);
  fillB2<<<dim3(T_, NB), 512, 0, stream>>>(ebin, cp, erec);

  for (int t0 = 0; t0 < T_; t0 += NT) {
    const int nt = (T_ - t0) < NT ? (T_ - t0) : NT;
    castx_kernel<<<dim3(2500, nt), 256, 0, stream>>>(x, xbt, t0);
    agg128<<<nt * 5000, 256, 0, stream>>>(xbt, P128, erec, cp, dinv, t0, nt);
    gemm_bf16<FIN_, false><<<dim3(313, 2, nt), 256, 0, stream>>>(P128, W1bT, b1, Q, nullptr, t0);
    agg256<<<nt * 5000, 256, 0, stream>>>(Q, P2, erec, cp, dinv, t0, nt);
    gemm_bf16<H_, true><<<dim3(313, 2, nt), 256, 0, stream>>>(P2, W2bT, b2, nullptr, emb, t0);
  }
  gx_kernel<<<T_, 768, 0, stream>>>(emb, WihT, bih, GX);
  gru2_kernel<<<1, 768, 0, stream>>>(GX, WhhT, bhh, Wc, bc, out);
}